// Round 13
// baseline (521.629 us; speedup 1.0000x reference)
//
#include <hip/hip_runtime.h>

#define NN 10000      // nodes
#define NE 320000     // edges
#define DD 128        // feature dim
#define NH 8          // heads

typedef __attribute__((ext_vector_type(8)))  __bf16        bf16x8;
typedef __attribute__((ext_vector_type(8)))  unsigned short ushort8v;
typedef __attribute__((ext_vector_type(16))) float         f32x16;

__device__ __forceinline__ unsigned short f2b(float f) {
  unsigned int b = __builtin_bit_cast(unsigned int, f);
  b += 0x7FFFu + ((b >> 16) & 1u);          // RNE to bf16
  return (unsigned short)(b >> 16);
}
__device__ __forceinline__ float b2f(unsigned short u) {
  return __builtin_bit_cast(float, (unsigned int)u << 16);
}
__device__ __forceinline__ f32x16 mfma32(bf16x8 a, bf16x8 b, f32x16 c) {
  return __builtin_amdgcn_mfma_f32_32x32x16_bf16(a, b, c, 0, 0, 0);
}
__device__ __forceinline__ float exp_fast(float x) {
  return __builtin_amdgcn_exp2f(x * 1.44269504f);
}
__device__ __forceinline__ float silu_fast(float x) {
  float e = __builtin_amdgcn_exp2f(x * -1.44269504f);
  return x * __builtin_amdgcn_rcpf(1.0f + e);
}

// ---- weights -> bf16 fragment-major + zero scratch counters ----
// Fragment-major: F[((slab*KS+ks)*64+lane)*8+j] = W[k][n],
//   k = ks*16 + (lane>>5)*8 + j, n = slab*32 + (lane&31)
__global__ __launch_bounds__(256) void prep_weights_k(
    const float* We1, const float* We2, const float* Wg,
    const float* Wq, const float* Wk, const float* Wv,
    const float* bq, const float* bk, const float* bv,
    unsigned short* W1F, unsigned short* W2F, unsigned short* WgT,
    unsigned short* WqkvF, float* bqkv, int* zr)
{
  int idx = blockIdx.x * 256 + threadIdx.x;
  if (idx < 49152) {                       // W1F: 4 slabs x 24 ksteps
    int j = idx & 7, lane = (idx >> 3) & 63;
    int ks = (idx >> 9) % 24, slab = idx / 12288;
    int k = ks * 16 + (lane >> 5) * 8 + j;
    int n = slab * 32 + (lane & 31);
    W1F[idx] = f2b(We1[k * 128 + n]);
  } else if (idx < 65536) {                // W2F: 4 slabs x 8 ksteps
    int o = idx - 49152;
    int j = o & 7, lane = (o >> 3) & 63;
    int ks = (o >> 9) & 7, slab = o >> 12;
    int k = ks * 16 + (lane >> 5) * 8 + j;
    int n = slab * 32 + (lane & 31);
    W2F[o] = f2b(We2[k * 128 + n]);
  } else if (idx < 69632) {                // WgT [n][k], n padded 8->32
    int o = idx - 65536;
    int n = o >> 7, k = o & 127;
    WgT[o] = (n < 8) ? f2b(Wg[k * 8 + n]) : (unsigned short)0;
  } else if (idx < 118784) {               // WqkvF: 12 slabs x 8 ksteps
    int o = idx - 69632;
    int j = o & 7, lane = (o >> 3) & 63;
    int ks = (o >> 9) & 7, s = o >> 12;    // s in 0..11
    int k = ks * 16 + (lane >> 5) * 8 + j;
    int n = (s & 3) * 32 + (lane & 31);
    const float* W = (s < 4) ? Wq : (s < 8) ? Wk : Wv;
    WqkvF[o] = f2b(W[k * 128 + n]);
  } else if (idx < 119168) {               // bqkv concat
    int i = idx - 118784;
    bqkv[i] = (i < 128) ? bq[i] : (i < 256) ? bk[i - 128] : bv[i - 256];
  } else if (idx < 119168 + 20008) {
    zr[idx - 119168] = 0;                  // deg + cursor + gsum
  }
}

// ---- node QKV projection via MFMA (swapped operands: lane = node, regs = cols) ----
__global__ __launch_bounds__(256) void node_proj_k(
    const float* h, const unsigned short* WqkvF, const float* bqkv,
    unsigned short* Qb, unsigned short* Kb, unsigned short* Vb)
{
  __shared__ unsigned short hb[32][136];
  int tid = threadIdx.x;
  int n0 = blockIdx.x * 32;
#pragma unroll
  for (int i = 0; i < 4; ++i) {            // 1024 float4 = 32 rows x 32
    int gi = tid + i * 256;
    int row = gi >> 5, c4 = gi & 31;
    ushort4 u{0, 0, 0, 0};
    if (n0 + row < NN) {
      float4 v = *(const float4*)(h + (size_t)(n0 + row) * DD + c4 * 4);
      u.x = f2b(v.x); u.y = f2b(v.y); u.z = f2b(v.z); u.w = f2b(v.w);
    }
    *(ushort4*)&hb[row][c4 * 4] = u;
  }
  __syncthreads();
  int wave = tid >> 6, lane = tid & 63;
  int la = lane & 31, hi = lane >> 5;
  f32x16 aq{}, ak{}, av{};
  const unsigned short* wq = WqkvF + (((size_t)(wave)     * 8) << 9) + lane * 8;
  const unsigned short* wk = WqkvF + (((size_t)(wave + 4) * 8) << 9) + lane * 8;
  const unsigned short* wv = WqkvF + (((size_t)(wave + 8) * 8) << 9) + lane * 8;
#pragma unroll
  for (int ks = 0; ks < 8; ++ks) {
    bf16x8 x = *(const bf16x8*)&hb[la][ks * 16 + hi * 8];
    aq = mfma32(*(const bf16x8*)(wq + (ks << 9)), x, aq);   // swapped
    ak = mfma32(*(const bf16x8*)(wk + (ks << 9)), x, ak);
    av = mfma32(*(const bf16x8*)(wv + (ks << 9)), x, av);
  }
  int node = n0 + la;
  if (node < NN) {
#pragma unroll
    for (int g = 0; g < 4; ++g) {
      int cq = wave * 32 + 4 * hi + 8 * g;
      float4 b4;
      ushort4 u;
      b4 = *(const float4*)(bqkv + cq);
      u.x = f2b(aq[4*g+0] + b4.x); u.y = f2b(aq[4*g+1] + b4.y);
      u.z = f2b(aq[4*g+2] + b4.z); u.w = f2b(aq[4*g+3] + b4.w);
      *(ushort4*)(Qb + (size_t)node * DD + cq) = u;
      b4 = *(const float4*)(bqkv + 128 + cq);
      u.x = f2b(ak[4*g+0] + b4.x); u.y = f2b(ak[4*g+1] + b4.y);
      u.z = f2b(ak[4*g+2] + b4.z); u.w = f2b(ak[4*g+3] + b4.w);
      *(ushort4*)(Kb + (size_t)node * DD + cq) = u;
      b4 = *(const float4*)(bqkv + 256 + cq);
      u.x = f2b(av[4*g+0] + b4.x); u.y = f2b(av[4*g+1] + b4.y);
      u.z = f2b(av[4*g+2] + b4.z); u.w = f2b(av[4*g+3] + b4.w);
      *(ushort4*)(Vb + (size_t)node * DD + cq) = u;
    }
  }
}

// ---- logitsT[h][e] = qk/4 + bg; also builds dst-degree histogram ----
__global__ __launch_bounds__(256) void qk_k(const int* ei, const unsigned short* Qb,
                                            const unsigned short* Kb,
                                            const float* bg, float* logitsT, int* deg)
{
  int e  = blockIdx.x * 32 + (threadIdx.x & 31);
  int h8 = threadIdx.x >> 5;
  int s  = ei[e];
  int d2 = ei[NE + e];
  if (h8 == 0) atomicAdd(&deg[d2], 1);
  const ushort8v* qr = (const ushort8v*)(Qb + (size_t)d2 * DD + h8 * 16);
  const ushort8v* kr = (const ushort8v*)(Kb + (size_t)s  * DD + h8 * 16);
  ushort8v q0 = qr[0], q1 = qr[1], k0 = kr[0], k1 = kr[1];
  float acc = 0.f;
#pragma unroll
  for (int j = 0; j < 8; ++j) {
    acc += b2f(q0[j]) * b2f(k0[j]) + b2f(q1[j]) * b2f(k1[j]);
  }
  logitsT[(size_t)h8 * NE + e] = acc * 0.25f + bg[h8];
}

// ---- t gate MFMA + exp -> edge-major expE, 8 waves / 128 edges (full occupancy) ----
// wave w stages rows 16w..16w+15; waves 0-3 run the gate MFMA; exp phase wave=head.
__global__ __launch_bounds__(512, 8) void t_gate_k(const float* t_ij,
                                                   const unsigned short* WgT,
                                                   const float* logitsT,
                                                   float* expE, float* gsum)
{
  __shared__ unsigned short T[128][136];
  __shared__ float Gs[8][132];             // [head][edge-row in block]
  int tid = threadIdx.x;
  int e0 = blockIdx.x * 128;
  int wave = tid >> 6, lane = tid & 63;
  int la = lane & 31, hi = lane >> 5;
  int r0s = wave * 16;
  const float4* tp = (const float4*)(t_ij + (size_t)(e0 + r0s) * DD);
#pragma unroll
  for (int i = 0; i < 8; ++i) {            // 512 float4 = 16 rows x 32
    int idx = lane + i * 64;
    float4 v = tp[idx];
    int row = r0s + (idx >> 5), c4 = idx & 31;
    ushort4 u; u.x = f2b(v.x); u.y = f2b(v.y); u.z = f2b(v.z); u.w = f2b(v.w);
    *(ushort4*)&T[row][c4 * 4] = u;
  }
  __syncthreads();
  if (wave < 4) {
    int r0 = wave * 32;
    f32x16 acc{};
    const unsigned short* wp = WgT + (size_t)la * DD + hi * 8;
#pragma unroll
    for (int ks = 0; ks < 8; ++ks) {
      bf16x8 a = *(const bf16x8*)&T[r0 + la][ks * 16 + hi * 8];
      bf16x8 b = *(const bf16x8*)(wp + ks * 16);
      acc = mfma32(a, b, acc);
    }
    if (la < 8) {
#pragma unroll
      for (int r = 0; r < 16; ++r) {
        int row = r0 + (r & 3) + 8 * (r >> 2) + 4 * hi;
        Gs[la][row] = acc[r];
      }
    }
  }
  __syncthreads();
  // exp phase: wave = head, lane covers 2 consecutive edges
  int hd = wave;
  int e2 = lane * 2;
  size_t ix = (size_t)hd * NE + e0 + e2;
  float2 lg = *(const float2*)(logitsT + ix);
  float ex0 = exp_fast(lg.x + Gs[hd][e2]);
  float ex1 = exp_fast(lg.y + Gs[hd][e2 + 1]);
  expE[(size_t)(e0 + e2) * NH + hd]     = ex0;
  expE[(size_t)(e0 + e2 + 1) * NH + hd] = ex1;
  float s = ex0 + ex1;
#pragma unroll
  for (int off = 32; off > 0; off >>= 1) s += __shfl_down(s, off, 64);
  if (lane == 0) atomicAdd(&gsum[hd], s);
}

// ---- single-block shuffle scan over deg -> exclusive offs; also rs = 1/gsum ----
__global__ __launch_bounds__(1024) void scan_k(const int* deg, int* offs,
                                               const float* gsum, float* rs) {
  __shared__ int ws[16];
  __shared__ int tot;
  int tid = threadIdx.x;
  if (tid < 8) rs[tid] = 1.0f / gsum[tid];
  int base = tid * 10;
  int v[10]; int s = 0;
#pragma unroll
  for (int j = 0; j < 10; ++j) {
    int i = base + j;
    int d = (i < NN) ? deg[i] : 0;
    v[j] = s; s += d;
  }
  int x = s;
#pragma unroll
  for (int off = 1; off < 64; off <<= 1) {
    int y = __shfl_up(x, off, 64);
    if ((tid & 63) >= off) x += y;        // inclusive wave scan
  }
  if ((tid & 63) == 63) ws[tid >> 6] = x;
  __syncthreads();
  if (tid == 0) {
    int c = 0;
#pragma unroll
    for (int k = 0; k < 16; ++k) { int t = ws[k]; ws[k] = c; c += t; }
    tot = c;
  }
  __syncthreads();
  int texcl = ws[tid >> 6] + (x - s);     // exclusive prefix of this thread's chunk
#pragma unroll
  for (int j = 0; j < 10; ++j) {
    int i = base + j;
    if (i < NN) offs[i] = texcl + v[j];
  }
  if (tid == 0) offs[NN] = tot;
}

__global__ __launch_bounds__(256) void bucket_k(const int* ei, const int* offs,
                                                int* cursor, int2* elist2) {
  int e = blockIdx.x * 256 + threadIdx.x;
  int s = ei[e];
  int d2 = ei[NE + e];
  int p = atomicAdd(&cursor[d2], 1);
  int2 es; es.x = e; es.y = s;
  elist2[offs[d2] + p] = es;
}

// ---- gather-sum per node: h_agg[n][d] = rs * sum_e expE[e][d/16] * V[src[e]][d] ----
__global__ __launch_bounds__(128) void aggregate_k(const int* offs, const int2* elist2,
                                                   const float* expE, const float* rs,
                                                   const unsigned short* Vb, float* h_agg)
{
  int n = blockIdx.x, d = threadIdx.x;
  float rsv = rs[d >> 4];
  int hplane = d >> 4;
  int st = offs[n], en = offs[n + 1];
  float acc = 0.f;
  for (int i = st; i < en; ++i) {
    int2 es = elist2[i];
    acc += expE[(size_t)es.x * NH + hplane] * b2f(Vb[(size_t)es.y * DD + d]);
  }
  h_agg[(size_t)n * DD + d] = acc * rsv;
}

// ---- h_new = h + h_agg @ Wo + bo  (f32 to d_out, bf16 copy for MLP) ----
__global__ __launch_bounds__(128) void hnew_k(const float* h, const float* h_agg,
                                              const float* Wo, const float* bo,
                                              float* out_h, unsigned short* hnb)
{
  __shared__ float ag[4][132];
  int g = threadIdx.x >> 5, la = threadIdx.x & 31;
  int n = blockIdx.x * 4 + g;
  float4 av = *(const float4*)(h_agg + (size_t)n * DD + la * 4);
  ag[g][la*4+0] = av.x; ag[g][la*4+1] = av.y; ag[g][la*4+2] = av.z; ag[g][la*4+3] = av.w;
  __syncthreads();
  float4 acc = *(const float4*)(bo + la * 4);
  for (int kk = 0; kk < DD; ++kk) {
    float a = ag[g][kk];
    float4 w = *(const float4*)(Wo + (size_t)kk * DD + la * 4);
    acc.x += a * w.x; acc.y += a * w.y; acc.z += a * w.z; acc.w += a * w.w;
  }
  float4 hv = *(const float4*)(h + (size_t)n * DD + la * 4);
  acc.x += hv.x; acc.y += hv.y; acc.z += hv.z; acc.w += hv.w;
  *(float4*)(out_h + (size_t)n * DD + la * 4) = acc;
  ushort4 u; u.x = f2b(acc.x); u.y = f2b(acc.y); u.z = f2b(acc.z); u.w = f2b(acc.w);
  *(ushort4*)(hnb + (size_t)n * DD + la * 4) = u;
}

// ---- edge MLP, 8 waves / 64 edges: wave = (row-half, col-slab), ONE chain ----
// Swapped operands (lane = edge, regs = 4-consecutive cols); W in registers
// (12+12 split, then W2); inner loop pure {ds_read + mfma}. 24 waves/CU LDS-allowed.
__global__ __launch_bounds__(512, 5) void edge_mlp_k(
    const int* ei, const unsigned short* hnb, const float* t_ij,
    const unsigned short* W1F, const unsigned short* W2F,
    const float* be1, const float* be2, float* t_out)
{
  __shared__ unsigned short Ah[64][264];   // cols 0..255 = h_src | h_dst (Y reuses cols 0..127)
  __shared__ unsigned short Tl[64][136];   // t section (A-frags + residual)
  __shared__ int sd[128];
  int tid = threadIdx.x;
  int e0 = blockIdx.x * 64;
  int lane = tid & 63, wave = tid >> 6;    // 8 waves
  int la = lane & 31, hi = lane >> 5;
  int wr = wave >> 2, wc = wave & 3;
  int r0 = wr * 32;

  const unsigned short* w1p = W1F + (((size_t)wc * 24) << 9) + lane * 8;
  bf16x8 Bf[12];
#pragma unroll
  for (int i = 0; i < 12; ++i) Bf[i] = *(const bf16x8*)(w1p + (i << 9));

  if (tid < 128) sd[tid] = (tid < 64) ? ei[e0 + tid] : ei[NE + e0 + tid - 64];
  __syncthreads();
#pragma unroll
  for (int i = 0; i < 4; ++i) {            // 2048 16B chunks for the two h sections
    int c = tid + i * 512;
    int sec = c >> 10;
    int row = (c >> 4) & 63;
    int cc = c & 15;
    int node = sd[sec * 64 + row];
    ushort8v val = *(const ushort8v*)(hnb + (size_t)node * DD + cc * 8);
    *(ushort8v*)&Ah[row][sec * 128 + cc * 8] = val;
  }
#pragma unroll
  for (int i = 0; i < 2; ++i) {            // t: f32 -> bf16 staging (1024 chunks)
    int c = tid + i * 512;
    int row = c >> 4, cc = c & 15;
    const float4* fp = (const float4*)(t_ij + (size_t)(e0 + row) * DD + cc * 8);
    float4 v0 = fp[0], v1 = fp[1];
    ushort4 u0; u0.x=f2b(v0.x); u0.y=f2b(v0.y); u0.z=f2b(v0.z); u0.w=f2b(v0.w);
    ushort4 u1; u1.x=f2b(v1.x); u1.y=f2b(v1.y); u1.z=f2b(v1.z); u1.w=f2b(v1.w);
    *(ushort4*)&Tl[row][cc * 8]     = u0;
    *(ushort4*)&Tl[row][cc * 8 + 4] = u1;
  }
  __syncthreads();
  f32x16 acc{};
#pragma unroll
  for (int ks = 0; ks < 12; ++ks) {        // K 0..191 from Ah
    bf16x8 x = *(const bf16x8*)&Ah[r0 + la][ks * 16 + hi * 8];
    acc = mfma32(Bf[ks], x, acc);
  }
#pragma unroll
  for (int i = 0; i < 12; ++i) Bf[i] = *(const bf16x8*)(w1p + ((12 + i) << 9));
#pragma unroll
  for (int i = 0; i < 12; ++i) {           // K 192..383: Ah tail then Tl
    int ks = 12 + i;
    bf16x8 x;
    if (ks < 16) x = *(const bf16x8*)&Ah[r0 + la][ks * 16 + hi * 8];
    else         x = *(const bf16x8*)&Tl[r0 + la][(ks - 16) * 16 + hi * 8];
    acc = mfma32(Bf[i], x, acc);
  }
  bf16x8 B2[8];
  const unsigned short* w2p = W2F + (((size_t)wc * 8) << 9) + lane * 8;
#pragma unroll
  for (int ks = 0; ks < 8; ++ks) B2[ks] = *(const bf16x8*)(w2p + (ks << 9));
  __syncthreads();                         // all Ah reads done; Y reuses cols 0..127
  // silu -> Y: lane owns edge r0+la; 4-consecutive cols per group, slab wc
#pragma unroll
  for (int g = 0; g < 4; ++g) {
    int nb = wc * 32 + 4 * hi + 8 * g;
    float4 bv = *(const float4*)(be1 + nb);
    ushort4 y;
    y.x = f2b(silu_fast(acc[4*g+0] + bv.x));
    y.y = f2b(silu_fast(acc[4*g+1] + bv.y));
    y.z = f2b(silu_fast(acc[4*g+2] + bv.z));
    y.w = f2b(silu_fast(acc[4*g+3] + bv.w));
    *(ushort4*)&Ah[r0 + la][nb] = y;
  }
  __syncthreads();
  f32x16 d{};
#pragma unroll
  for (int ks = 0; ks < 8; ++ks) {
    bf16x8 x = *(const bf16x8*)&Ah[r0 + la][ks * 16 + hi * 8];
    d = mfma32(B2[ks], x, d);
  }
  // epilogue: residual (b64 LDS) + bias + float4 stores
#pragma unroll
  for (int g = 0; g < 4; ++g) {
    int nb = wc * 32 + 4 * hi + 8 * g;
    float4 bv = *(const float4*)(be2 + nb);
    ushort4 r = *(const ushort4*)&Tl[r0 + la][nb];
    float4 o;
    o.x = b2f(r.x) + d[4*g+0] + bv.x;
    o.y = b2f(r.y) + d[4*g+1] + bv.y;
    o.z = b2f(r.z) + d[4*g+2] + bv.z;
    o.w = b2f(r.w) + d[4*g+3] + bv.w;
    *(float4*)(t_out + (size_t)(e0 + r0 + la) * DD + nb) = o;
  }
}

extern "C" void kernel_launch(void* const* d_in, const int* in_sizes, int n_in,
                              void* d_out, int out_size, void* d_ws, size_t ws_size,
                              hipStream_t stream)
{
  const int*   ei   = (const int*)d_in[0];
  const float* h    = (const float*)d_in[1];
  const float* t_ij = (const float*)d_in[2];
  const float* Wq = (const float*)d_in[3];
  const float* bq = (const float*)d_in[4];
  const float* Wk = (const float*)d_in[5];
  const float* bk = (const float*)d_in[6];
  const float* Wv = (const float*)d_in[7];
  const float* bv = (const float*)d_in[8];
  const float* Wg = (const float*)d_in[9];
  const float* bg = (const float*)d_in[10];
  const float* Wo = (const float*)d_in[11];
  const float* bo = (const float*)d_in[12];
  const float* We1 = (const float*)d_in[13];
  const float* be1 = (const float*)d_in[14];
  const float* We2 = (const float*)d_in[15];
  const float* be2 = (const float*)d_in[16];

  char* base = (char*)d_ws;
  size_t o = 0;
  auto take = [&](size_t bytes) -> void* {
    void* p = base + o;
    o = (o + bytes + 255) & ~(size_t)255;
    return p;
  };
  unsigned short* Qb = (unsigned short*)take((size_t)NN * DD * 2);
  unsigned short* Kb = (unsigned short*)take((size_t)NN * DD * 2);
  unsigned short* Vb = (unsigned short*)take((size_t)NN * DD * 2);
  float* logitsT = (float*)take((size_t)NH * NE * 4);
  float* expE    = (float*)take((size_t)NE * NH * 4);   // edge-major alpha
  float* rs      = (float*)take(256);
  float* h_agg   = (float*)take((size_t)NN * DD * 4);
  // zero region: deg + cursor + gsum contiguous (zeroed by prep_weights_k)
  char* zbase = base + o;
  int*   deg    = (int*)zbase;
  int*   cursor = (int*)(zbase + (size_t)NN * 4);
  float* gsum   = (float*)(zbase + (size_t)NN * 8);
  size_t zbytes = (size_t)(NN * 2 + 8) * 4;     // 20008 ints
  o = (o + zbytes + 255) & ~(size_t)255;
  int* offs    = (int*)take((size_t)(NN + 1) * 4);
  int2* elist2 = (int2*)take((size_t)NE * 8);
  unsigned short* hnb   = (unsigned short*)take((size_t)NN * DD * 2);
  unsigned short* W1F   = (unsigned short*)take(49152 * 2);
  unsigned short* W2F   = (unsigned short*)take(16384 * 2);
  unsigned short* WgT   = (unsigned short*)take(4096 * 2);
  unsigned short* WqkvF = (unsigned short*)take(49152 * 2);
  float*          bqkv  = (float*)take(384 * 4);

  float* out_h = (float*)d_out;
  float* t_out = out_h + (size_t)NN * DD;

  prep_weights_k<<<544, 256, 0, stream>>>(We1, We2, Wg, Wq, Wk, Wv, bq, bk, bv,
                                          W1F, W2F, WgT, WqkvF, bqkv, (int*)zbase);
  node_proj_k<<<(NN + 31) / 32, 256, 0, stream>>>(h, WqkvF, bqkv, Qb, Kb, Vb);
  qk_k<<<NE / 32, 256, 0, stream>>>(ei, Qb, Kb, bg, logitsT, deg);
  t_gate_k<<<NE / 128, 512, 0, stream>>>(t_ij, WgT, logitsT, expE, gsum);
  scan_k<<<1, 1024, 0, stream>>>(deg, offs, gsum, rs);
  bucket_k<<<NE / 256, 256, 0, stream>>>(ei, offs, cursor, elist2);
  aggregate_k<<<NN, 128, 0, stream>>>(offs, elist2, expE, rs, Vb, h_agg);
  hnew_k<<<NN / 4, 128, 0, stream>>>(h, h_agg, Wo, bo, out_h, hnb);
  edge_mlp_k<<<NE / 64, 512, 0, stream>>>(ei, hnb, t_ij, W1F, W2F, be1, be2, t_out);
}

// Round 14
// 285.219 us; speedup vs baseline: 1.8289x; 1.8289x over previous
//
#include <hip/hip_runtime.h>

#define NN 10000      // nodes
#define NE 320000     // edges
#define DD 128        // feature dim
#define NH 8          // heads

typedef __attribute__((ext_vector_type(8)))  __bf16        bf16x8;
typedef __attribute__((ext_vector_type(8)))  unsigned short ushort8v;
typedef __attribute__((ext_vector_type(16))) float         f32x16;

__device__ __forceinline__ unsigned short f2b(float f) {
  unsigned int b = __builtin_bit_cast(unsigned int, f);
  b += 0x7FFFu + ((b >> 16) & 1u);          // RNE to bf16
  return (unsigned short)(b >> 16);
}
__device__ __forceinline__ float b2f(unsigned short u) {
  return __builtin_bit_cast(float, (unsigned int)u << 16);
}
__device__ __forceinline__ f32x16 mfma32(bf16x8 a, bf16x8 b, f32x16 c) {
  return __builtin_amdgcn_mfma_f32_32x32x16_bf16(a, b, c, 0, 0, 0);
}
__device__ __forceinline__ float exp_fast(float x) {
  return __builtin_amdgcn_exp2f(x * 1.44269504f);
}
__device__ __forceinline__ float silu_fast(float x) {
  float e = __builtin_amdgcn_exp2f(x * -1.44269504f);
  return x * __builtin_amdgcn_rcpf(1.0f + e);
}

// ---- weights -> bf16 fragment-major + zero scratch counters ----
// Fragment-major: F[((slab*KS+ks)*64+lane)*8+j] = W[k][n],
//   k = ks*16 + (lane>>5)*8 + j, n = slab*32 + (lane&31)
__global__ __launch_bounds__(256) void prep_weights_k(
    const float* We1, const float* We2, const float* Wg,
    const float* Wq, const float* Wk, const float* Wv,
    const float* bq, const float* bk, const float* bv,
    unsigned short* W1F, unsigned short* W2F, unsigned short* WgT,
    unsigned short* WqkvF, float* bqkv, int* zr)
{
  int idx = blockIdx.x * 256 + threadIdx.x;
  if (idx < 49152) {                       // W1F: 4 slabs x 24 ksteps
    int j = idx & 7, lane = (idx >> 3) & 63;
    int ks = (idx >> 9) % 24, slab = idx / 12288;
    int k = ks * 16 + (lane >> 5) * 8 + j;
    int n = slab * 32 + (lane & 31);
    W1F[idx] = f2b(We1[k * 128 + n]);
  } else if (idx < 65536) {                // W2F: 4 slabs x 8 ksteps
    int o = idx - 49152;
    int j = o & 7, lane = (o >> 3) & 63;
    int ks = (o >> 9) & 7, slab = o >> 12;
    int k = ks * 16 + (lane >> 5) * 8 + j;
    int n = slab * 32 + (lane & 31);
    W2F[o] = f2b(We2[k * 128 + n]);
  } else if (idx < 69632) {                // WgT [n][k], n padded 8->32
    int o = idx - 65536;
    int n = o >> 7, k = o & 127;
    WgT[o] = (n < 8) ? f2b(Wg[k * 8 + n]) : (unsigned short)0;
  } else if (idx < 118784) {               // WqkvF: 12 slabs x 8 ksteps
    int o = idx - 69632;
    int j = o & 7, lane = (o >> 3) & 63;
    int ks = (o >> 9) & 7, s = o >> 12;    // s in 0..11
    int k = ks * 16 + (lane >> 5) * 8 + j;
    int n = (s & 3) * 32 + (lane & 31);
    const float* W = (s < 4) ? Wq : (s < 8) ? Wk : Wv;
    WqkvF[o] = f2b(W[k * 128 + n]);
  } else if (idx < 119168) {               // bqkv concat
    int i = idx - 118784;
    bqkv[i] = (i < 128) ? bq[i] : (i < 256) ? bk[i - 128] : bv[i - 256];
  } else if (idx < 119168 + 20008) {
    zr[idx - 119168] = 0;                  // deg + cursor + gsum
  }
}

// ---- node QKV projection via MFMA (swapped operands: lane = node, regs = cols) ----
__global__ __launch_bounds__(256) void node_proj_k(
    const float* h, const unsigned short* WqkvF, const float* bqkv,
    unsigned short* Qb, unsigned short* Kb, unsigned short* Vb)
{
  __shared__ unsigned short hb[32][136];
  int tid = threadIdx.x;
  int n0 = blockIdx.x * 32;
#pragma unroll
  for (int i = 0; i < 4; ++i) {            // 1024 float4 = 32 rows x 32
    int gi = tid + i * 256;
    int row = gi >> 5, c4 = gi & 31;
    ushort4 u{0, 0, 0, 0};
    if (n0 + row < NN) {
      float4 v = *(const float4*)(h + (size_t)(n0 + row) * DD + c4 * 4);
      u.x = f2b(v.x); u.y = f2b(v.y); u.z = f2b(v.z); u.w = f2b(v.w);
    }
    *(ushort4*)&hb[row][c4 * 4] = u;
  }
  __syncthreads();
  int wave = tid >> 6, lane = tid & 63;
  int la = lane & 31, hi = lane >> 5;
  f32x16 aq{}, ak{}, av{};
  const unsigned short* wq = WqkvF + (((size_t)(wave)     * 8) << 9) + lane * 8;
  const unsigned short* wk = WqkvF + (((size_t)(wave + 4) * 8) << 9) + lane * 8;
  const unsigned short* wv = WqkvF + (((size_t)(wave + 8) * 8) << 9) + lane * 8;
#pragma unroll
  for (int ks = 0; ks < 8; ++ks) {
    bf16x8 x = *(const bf16x8*)&hb[la][ks * 16 + hi * 8];
    aq = mfma32(*(const bf16x8*)(wq + (ks << 9)), x, aq);   // swapped
    ak = mfma32(*(const bf16x8*)(wk + (ks << 9)), x, ak);
    av = mfma32(*(const bf16x8*)(wv + (ks << 9)), x, av);
  }
  int node = n0 + la;
  if (node < NN) {
#pragma unroll
    for (int g = 0; g < 4; ++g) {
      int cq = wave * 32 + 4 * hi + 8 * g;
      float4 b4;
      ushort4 u;
      b4 = *(const float4*)(bqkv + cq);
      u.x = f2b(aq[4*g+0] + b4.x); u.y = f2b(aq[4*g+1] + b4.y);
      u.z = f2b(aq[4*g+2] + b4.z); u.w = f2b(aq[4*g+3] + b4.w);
      *(ushort4*)(Qb + (size_t)node * DD + cq) = u;
      b4 = *(const float4*)(bqkv + 128 + cq);
      u.x = f2b(ak[4*g+0] + b4.x); u.y = f2b(ak[4*g+1] + b4.y);
      u.z = f2b(ak[4*g+2] + b4.z); u.w = f2b(ak[4*g+3] + b4.w);
      *(ushort4*)(Kb + (size_t)node * DD + cq) = u;
      b4 = *(const float4*)(bqkv + 256 + cq);
      u.x = f2b(av[4*g+0] + b4.x); u.y = f2b(av[4*g+1] + b4.y);
      u.z = f2b(av[4*g+2] + b4.z); u.w = f2b(av[4*g+3] + b4.w);
      *(ushort4*)(Vb + (size_t)node * DD + cq) = u;
    }
  }
}

// ---- logitsT[h][e] = qk/4 + bg; also builds dst-degree histogram ----
__global__ __launch_bounds__(256) void qk_k(const int* ei, const unsigned short* Qb,
                                            const unsigned short* Kb,
                                            const float* bg, float* logitsT, int* deg)
{
  int e  = blockIdx.x * 32 + (threadIdx.x & 31);
  int h8 = threadIdx.x >> 5;
  int s  = ei[e];
  int d2 = ei[NE + e];
  if (h8 == 0) atomicAdd(&deg[d2], 1);
  const ushort8v* qr = (const ushort8v*)(Qb + (size_t)d2 * DD + h8 * 16);
  const ushort8v* kr = (const ushort8v*)(Kb + (size_t)s  * DD + h8 * 16);
  ushort8v q0 = qr[0], q1 = qr[1], k0 = kr[0], k1 = kr[1];
  float acc = 0.f;
#pragma unroll
  for (int j = 0; j < 8; ++j) {
    acc += b2f(q0[j]) * b2f(k0[j]) + b2f(q1[j]) * b2f(k1[j]);
  }
  logitsT[(size_t)h8 * NE + e] = acc * 0.25f + bg[h8];
}

// ---- t gate MFMA + exp -> edge-major expE; 512 thr, (512,4): VGPR cap 64,
// 4 blocks x 8 waves = 32 waves/CU. Staging 8 float4/thread (in-flight OK). ----
__global__ __launch_bounds__(512, 4) void t_gate_k(const float* t_ij,
                                                   const unsigned short* WgT,
                                                   const float* logitsT,
                                                   float* expE, float* gsum)
{
  __shared__ unsigned short T[128][136];
  __shared__ float Gs[8][132];             // [head][edge-row in block]
  __shared__ float hpart[8];
  int tid = threadIdx.x;
  int e0 = blockIdx.x * 128;
  if (tid < 8) hpart[tid] = 0.f;
  const float4* tp = (const float4*)(t_ij + (size_t)e0 * DD);
#pragma unroll
  for (int i = 0; i < 8; ++i) {            // 4096 float4 = 128 rows x 32
    int gi = tid + i * 512;
    float4 v = tp[gi];
    int row = gi >> 5, c4 = gi & 31;
    ushort4 u; u.x = f2b(v.x); u.y = f2b(v.y); u.z = f2b(v.z); u.w = f2b(v.w);
    *(ushort4*)&T[row][c4 * 4] = u;
  }
  __syncthreads();
  int wave = tid >> 6, lane = tid & 63;
  int la = lane & 31, hi = lane >> 5;
  if (wave < 4) {                          // gate MFMA on 4 sub-tiles
    int r0 = wave * 32;
    f32x16 acc{};
    const unsigned short* wp = WgT + (size_t)la * DD + hi * 8;
#pragma unroll
    for (int ks = 0; ks < 8; ++ks) {
      bf16x8 a = *(const bf16x8*)&T[r0 + la][ks * 16 + hi * 8];
      bf16x8 b = *(const bf16x8*)(wp + ks * 16);
      acc = mfma32(a, b, acc);
    }
    if (la < 8) {
#pragma unroll
      for (int r = 0; r < 16; ++r) {
        int row = r0 + (r & 3) + 8 * (r >> 2) + 4 * hi;
        Gs[la][row] = acc[r];
      }
    }
  }
  __syncthreads();
  // exp phase: thread = (edge el = tid>>2, head-pair part = tid&3)
  // -> float2 store stream into expE is fully contiguous across the block.
  int el = tid >> 2, part = tid & 3;
  int h0 = part * 2;
  float g0 = Gs[h0][el], g1 = Gs[h0 + 1][el];
  float l0 = logitsT[(size_t)h0 * NE + e0 + el];
  float l1 = logitsT[(size_t)(h0 + 1) * NE + e0 + el];
  float ex0 = exp_fast(l0 + g0);
  float ex1 = exp_fast(l1 + g1);
  float2 st; st.x = ex0; st.y = ex1;
  *(float2*)(expE + (size_t)(e0 + el) * NH + h0) = st;
  // reduce over edges: lanes with equal (lane&3) via xor 4,8,16,32
  float s0 = ex0, s1 = ex1;
#pragma unroll
  for (int off = 4; off < 64; off <<= 1) {
    s0 += __shfl_xor(s0, off, 64);
    s1 += __shfl_xor(s1, off, 64);
  }
  if (lane < 4) {
    atomicAdd(&hpart[part * 2], s0);
    atomicAdd(&hpart[part * 2 + 1], s1);
  }
  __syncthreads();
  if (tid < 8) atomicAdd(&gsum[tid], hpart[tid]);
}

// ---- single-block shuffle scan over deg -> exclusive offs; also rs = 1/gsum ----
__global__ __launch_bounds__(1024) void scan_k(const int* deg, int* offs,
                                               const float* gsum, float* rs) {
  __shared__ int ws[16];
  __shared__ int tot;
  int tid = threadIdx.x;
  if (tid < 8) rs[tid] = 1.0f / gsum[tid];
  int base = tid * 10;
  int v[10]; int s = 0;
#pragma unroll
  for (int j = 0; j < 10; ++j) {
    int i = base + j;
    int d = (i < NN) ? deg[i] : 0;
    v[j] = s; s += d;
  }
  int x = s;
#pragma unroll
  for (int off = 1; off < 64; off <<= 1) {
    int y = __shfl_up(x, off, 64);
    if ((tid & 63) >= off) x += y;        // inclusive wave scan
  }
  if ((tid & 63) == 63) ws[tid >> 6] = x;
  __syncthreads();
  if (tid == 0) {
    int c = 0;
#pragma unroll
    for (int k = 0; k < 16; ++k) { int t = ws[k]; ws[k] = c; c += t; }
    tot = c;
  }
  __syncthreads();
  int texcl = ws[tid >> 6] + (x - s);     // exclusive prefix of this thread's chunk
#pragma unroll
  for (int j = 0; j < 10; ++j) {
    int i = base + j;
    if (i < NN) offs[i] = texcl + v[j];
  }
  if (tid == 0) offs[NN] = tot;
}

__global__ __launch_bounds__(256) void bucket_k(const int* ei, const int* offs,
                                                int* cursor, int2* elist2) {
  int e = blockIdx.x * 256 + threadIdx.x;
  int s = ei[e];
  int d2 = ei[NE + e];
  int p = atomicAdd(&cursor[d2], 1);
  int2 es; es.x = e; es.y = s;
  elist2[offs[d2] + p] = es;
}

// ---- gather-sum per node: h_agg[n][d] = rs * sum_e expE[e][d/16] * V[src[e]][d] ----
__global__ __launch_bounds__(128) void aggregate_k(const int* offs, const int2* elist2,
                                                   const float* expE, const float* rs,
                                                   const unsigned short* Vb, float* h_agg)
{
  int n = blockIdx.x, d = threadIdx.x;
  float rsv = rs[d >> 4];
  int hplane = d >> 4;
  int st = offs[n], en = offs[n + 1];
  float acc = 0.f;
  for (int i = st; i < en; ++i) {
    int2 es = elist2[i];
    acc += expE[(size_t)es.x * NH + hplane] * b2f(Vb[(size_t)es.y * DD + d]);
  }
  h_agg[(size_t)n * DD + d] = acc * rsv;
}

// ---- h_new = h + h_agg @ Wo + bo  (f32 to d_out, bf16 copy for MLP) ----
__global__ __launch_bounds__(128) void hnew_k(const float* h, const float* h_agg,
                                              const float* Wo, const float* bo,
                                              float* out_h, unsigned short* hnb)
{
  __shared__ float ag[4][132];
  int g = threadIdx.x >> 5, la = threadIdx.x & 31;
  int n = blockIdx.x * 4 + g;
  float4 av = *(const float4*)(h_agg + (size_t)n * DD + la * 4);
  ag[g][la*4+0] = av.x; ag[g][la*4+1] = av.y; ag[g][la*4+2] = av.z; ag[g][la*4+3] = av.w;
  __syncthreads();
  float4 acc = *(const float4*)(bo + la * 4);
  for (int kk = 0; kk < DD; ++kk) {
    float a = ag[g][kk];
    float4 w = *(const float4*)(Wo + (size_t)kk * DD + la * 4);
    acc.x += a * w.x; acc.y += a * w.y; acc.z += a * w.z; acc.w += a * w.w;
  }
  float4 hv = *(const float4*)(h + (size_t)n * DD + la * 4);
  acc.x += hv.x; acc.y += hv.y; acc.z += hv.z; acc.w += hv.w;
  *(float4*)(out_h + (size_t)n * DD + la * 4) = acc;
  ushort4 u; u.x = f2b(acc.x); u.y = f2b(acc.y); u.z = f2b(acc.z); u.w = f2b(acc.w);
  *(ushort4*)(hnb + (size_t)n * DD + la * 4) = u;
}

// ---- edge MLP (swapped operands, split W1 preload): t from f32 t_ij ----
__global__ __launch_bounds__(256, 3) void edge_mlp_k(
    const int* ei, const unsigned short* hnb, const float* t_ij,
    const unsigned short* W1F, const unsigned short* W2F,
    const float* be1, const float* be2, float* t_out)
{
  __shared__ unsigned short Ah[64][264];   // cols 0..255 = h_src | h_dst (reused as Y)
  __shared__ unsigned short Tl[64][136];   // t section (A-frags + residual)
  __shared__ int sd[128];
  int tid = threadIdx.x;
  int e0 = blockIdx.x * 64;
  int lane = tid & 63, wave = tid >> 6;
  int la = lane & 31, hi = lane >> 5;
  int n0 = wave * 32;

  const unsigned short* w1p = W1F + (((size_t)wave * 24) << 9) + lane * 8;
  bf16x8 Bf[12];
#pragma unroll
  for (int i = 0; i < 12; ++i) Bf[i] = *(const bf16x8*)(w1p + (i << 9));

  if (tid < 128) sd[tid] = (tid < 64) ? ei[e0 + tid] : ei[NE + e0 + tid - 64];
  __syncthreads();
#pragma unroll
  for (int i = 0; i < 8; ++i) {            // 2048 16B chunks for the two h sections
    int c = tid + i * 256;
    int sec = c >> 10;
    int row = (c >> 4) & 63;
    int cc = c & 15;
    int node = sd[sec * 64 + row];
    ushort8v val = *(const ushort8v*)(hnb + (size_t)node * DD + cc * 8);
    *(ushort8v*)&Ah[row][sec * 128 + cc * 8] = val;
  }
#pragma unroll
  for (int i = 0; i < 4; ++i) {            // t: f32 -> bf16 staging
    int c = tid + i * 256;
    int row = c >> 4, cc = c & 15;
    const float4* fp = (const float4*)(t_ij + (size_t)(e0 + row) * DD + cc * 8);
    float4 v0 = fp[0], v1 = fp[1];
    ushort4 u0; u0.x=f2b(v0.x); u0.y=f2b(v0.y); u0.z=f2b(v0.z); u0.w=f2b(v0.w);
    ushort4 u1; u1.x=f2b(v1.x); u1.y=f2b(v1.y); u1.z=f2b(v1.z); u1.w=f2b(v1.w);
    *(ushort4*)&Tl[row][cc * 8]     = u0;
    *(ushort4*)&Tl[row][cc * 8 + 4] = u1;
  }
  __syncthreads();
  f32x16 acc0{}, acc1{};
#pragma unroll
  for (int ks = 0; ks < 12; ++ks) {        // K 0..191 from Ah
    bf16x8 x0 = *(const bf16x8*)&Ah[la][ks * 16 + hi * 8];
    bf16x8 x1 = *(const bf16x8*)&Ah[la + 32][ks * 16 + hi * 8];
    acc0 = mfma32(Bf[ks], x0, acc0);
    acc1 = mfma32(Bf[ks], x1, acc1);
  }
#pragma unroll
  for (int i = 0; i < 12; ++i) Bf[i] = *(const bf16x8*)(w1p + ((12 + i) << 9));
#pragma unroll
  for (int i = 0; i < 12; ++i) {           // K 192..383: Ah tail then Tl
    int ks = 12 + i;
    bf16x8 x0, x1;
    if (ks < 16) {
      x0 = *(const bf16x8*)&Ah[la][ks * 16 + hi * 8];
      x1 = *(const bf16x8*)&Ah[la + 32][ks * 16 + hi * 8];
    } else {
      x0 = *(const bf16x8*)&Tl[la][(ks - 16) * 16 + hi * 8];
      x1 = *(const bf16x8*)&Tl[la + 32][(ks - 16) * 16 + hi * 8];
    }
    acc0 = mfma32(Bf[i], x0, acc0);
    acc1 = mfma32(Bf[i], x1, acc1);
  }
  bf16x8 B2[8];
  const unsigned short* w2p = W2F + (((size_t)wave * 8) << 9) + lane * 8;
#pragma unroll
  for (int ks = 0; ks < 8; ++ks) B2[ks] = *(const bf16x8*)(w2p + (ks << 9));
  __syncthreads();                         // all Ah reads done; reuse as Y
  // silu -> Y: lane owns edge la / la+32; 4-consecutive cols per group
#pragma unroll
  for (int g = 0; g < 4; ++g) {
    int nb = n0 + 4 * hi + 8 * g;
    float4 bv = *(const float4*)(be1 + nb);
    ushort4 y0;
    y0.x = f2b(silu_fast(acc0[4*g+0] + bv.x));
    y0.y = f2b(silu_fast(acc0[4*g+1] + bv.y));
    y0.z = f2b(silu_fast(acc0[4*g+2] + bv.z));
    y0.w = f2b(silu_fast(acc0[4*g+3] + bv.w));
    *(ushort4*)&Ah[la][nb] = y0;
    ushort4 y1;
    y1.x = f2b(silu_fast(acc1[4*g+0] + bv.x));
    y1.y = f2b(silu_fast(acc1[4*g+1] + bv.y));
    y1.z = f2b(silu_fast(acc1[4*g+2] + bv.z));
    y1.w = f2b(silu_fast(acc1[4*g+3] + bv.w));
    *(ushort4*)&Ah[la + 32][nb] = y1;
  }
  __syncthreads();
  f32x16 d0{}, d1{};
#pragma unroll
  for (int ks = 0; ks < 8; ++ks) {
    bf16x8 x0 = *(const bf16x8*)&Ah[la][ks * 16 + hi * 8];
    bf16x8 x1 = *(const bf16x8*)&Ah[la + 32][ks * 16 + hi * 8];
    d0 = mfma32(B2[ks], x0, d0);
    d1 = mfma32(B2[ks], x1, d1);
  }
  // epilogue: residual (b64 LDS) + bias + float4 stores
#pragma unroll
  for (int g = 0; g < 4; ++g) {
    int nb = n0 + 4 * hi + 8 * g;
    float4 bv = *(const float4*)(be2 + nb);
    ushort4 r0 = *(const ushort4*)&Tl[la][nb];
    float4 o0;
    o0.x = b2f(r0.x) + d0[4*g+0] + bv.x;
    o0.y = b2f(r0.y) + d0[4*g+1] + bv.y;
    o0.z = b2f(r0.z) + d0[4*g+2] + bv.z;
    o0.w = b2f(r0.w) + d0[4*g+3] + bv.w;
    *(float4*)(t_out + (size_t)(e0 + la) * DD + nb) = o0;
    ushort4 r1 = *(const ushort4*)&Tl[la + 32][nb];
    float4 o1;
    o1.x = b2f(r1.x) + d1[4*g+0] + bv.x;
    o1.y = b2f(r1.y) + d1[4*g+1] + bv.y;
    o1.z = b2f(r1.z) + d1[4*g+2] + bv.z;
    o1.w = b2f(r1.w) + d1[4*g+3] + bv.w;
    *(float4*)(t_out + (size_t)(e0 + la + 32) * DD + nb) = o1;
  }
}

extern "C" void kernel_launch(void* const* d_in, const int* in_sizes, int n_in,
                              void* d_out, int out_size, void* d_ws, size_t ws_size,
                              hipStream_t stream)
{
  const int*   ei   = (const int*)d_in[0];
  const float* h    = (const float*)d_in[1];
  const float* t_ij = (const float*)d_in[2];
  const float* Wq = (const float*)d_in[3];
  const float* bq = (const float*)d_in[4];
  const float* Wk = (const float*)d_in[5];
  const float* bk = (const float*)d_in[6];
  const float* Wv = (const float*)d_in[7];
  const float* bv = (const float*)d_in[8];
  const float* Wg = (const float*)d_in[9];
  const float* bg = (const float*)d_in[10];
  const float* Wo = (const float*)d_in[11];
  const float* bo = (const float*)d_in[12];
  const float* We1 = (const float*)d_in[13];
  const float* be1 = (const float*)d_in[14];
  const float* We2 = (const float*)d_in[15];
  const float* be2 = (const float*)d_in[16];

  char* base = (char*)d_ws;
  size_t o = 0;
  auto take = [&](size_t bytes) -> void* {
    void* p = base + o;
    o = (o + bytes + 255) & ~(size_t)255;
    return p;
  };
  unsigned short* Qb = (unsigned short*)take((size_t)NN * DD * 2);
  unsigned short* Kb = (unsigned short*)take((size_t)NN * DD * 2);
  unsigned short* Vb = (unsigned short*)take((size_t)NN * DD * 2);
  float* logitsT = (float*)take((size_t)NH * NE * 4);
  float* expE    = (float*)take((size_t)NE * NH * 4);   // edge-major alpha
  float* rs      = (float*)take(256);
  float* h_agg   = (float*)take((size_t)NN * DD * 4);
  // zero region: deg + cursor + gsum contiguous (zeroed by prep_weights_k)
  char* zbase = base + o;
  int*   deg    = (int*)zbase;
  int*   cursor = (int*)(zbase + (size_t)NN * 4);
  float* gsum   = (float*)(zbase + (size_t)NN * 8);
  size_t zbytes = (size_t)(NN * 2 + 8) * 4;     // 20008 ints
  o = (o + zbytes + 255) & ~(size_t)255;
  int* offs    = (int*)take((size_t)(NN + 1) * 4);
  int2* elist2 = (int2*)take((size_t)NE * 8);
  unsigned short* hnb   = (unsigned short*)take((size_t)NN * DD * 2);
  unsigned short* W1F   = (unsigned short*)take(49152 * 2);
  unsigned short* W2F   = (unsigned short*)take(16384 * 2);
  unsigned short* WgT   = (unsigned short*)take(4096 * 2);
  unsigned short* WqkvF = (unsigned short*)take(49152 * 2);
  float*          bqkv  = (float*)take(384 * 4);

  float* out_h = (float*)d_out;
  float* t_out = out_h + (size_t)NN * DD;

  prep_weights_k<<<544, 256, 0, stream>>>(We1, We2, Wg, Wq, Wk, Wv, bq, bk, bv,
                                          W1F, W2F, WgT, WqkvF, bqkv, (int*)zbase);
  node_proj_k<<<(NN + 31) / 32, 256, 0, stream>>>(h, WqkvF, bqkv, Qb, Kb, Vb);
  qk_k<<<NE / 32, 256, 0, stream>>>(ei, Qb, Kb, bg, logitsT, deg);
  t_gate_k<<<NE / 128, 512, 0, stream>>>(t_ij, WgT, logitsT, expE, gsum);
  scan_k<<<1, 1024, 0, stream>>>(deg, offs, gsum, rs);
  bucket_k<<<NE / 256, 256, 0, stream>>>(ei, offs, cursor, elist2);
  aggregate_k<<<NN, 128, 0, stream>>>(offs, elist2, expE, rs, Vb, h_agg);
  hnew_k<<<NN / 4, 128, 0, stream>>>(h, h_agg, Wo, bo, out_h, hnb);
  edge_mlp_k<<<NE / 64, 256, 0, stream>>>(ei, hnb, t_ij, W1F, W2F, be1, be2, t_out);
}

// Round 15
// 279.995 us; speedup vs baseline: 1.8630x; 1.0187x over previous
//
#include <hip/hip_runtime.h>

#define NN 10000      // nodes
#define NE 320000     // edges
#define DD 128        // feature dim
#define NH 8          // heads

typedef __attribute__((ext_vector_type(8)))  __bf16        bf16x8;
typedef __attribute__((ext_vector_type(8)))  unsigned short ushort8v;
typedef __attribute__((ext_vector_type(16))) float         f32x16;

__device__ __forceinline__ unsigned short f2b(float f) {
  unsigned int b = __builtin_bit_cast(unsigned int, f);
  b += 0x7FFFu + ((b >> 16) & 1u);          // RNE to bf16
  return (unsigned short)(b >> 16);
}
__device__ __forceinline__ float b2f(unsigned short u) {
  return __builtin_bit_cast(float, (unsigned int)u << 16);
}
__device__ __forceinline__ f32x16 mfma32(bf16x8 a, bf16x8 b, f32x16 c) {
  return __builtin_amdgcn_mfma_f32_32x32x16_bf16(a, b, c, 0, 0, 0);
}
__device__ __forceinline__ float exp_fast(float x) {
  return __builtin_amdgcn_exp2f(x * 1.44269504f);
}
__device__ __forceinline__ float silu_fast(float x) {
  float e = __builtin_amdgcn_exp2f(x * -1.44269504f);
  return x * __builtin_amdgcn_rcpf(1.0f + e);
}

// ---- weights -> bf16 fragment-major + zero scratch counters ----
// Fragment-major: F[((slab*KS+ks)*64+lane)*8+j] = W[k][n],
//   k = ks*16 + (lane>>5)*8 + j, n = slab*32 + (lane&31)
__global__ __launch_bounds__(256) void prep_weights_k(
    const float* We1, const float* We2, const float* Wg,
    const float* Wq, const float* Wk, const float* Wv,
    const float* bq, const float* bk, const float* bv,
    unsigned short* W1F, unsigned short* W2F, unsigned short* WgT,
    unsigned short* WqkvF, float* bqkv, int* zr)
{
  int idx = blockIdx.x * 256 + threadIdx.x;
  if (idx < 49152) {                       // W1F: 4 slabs x 24 ksteps
    int j = idx & 7, lane = (idx >> 3) & 63;
    int ks = (idx >> 9) % 24, slab = idx / 12288;
    int k = ks * 16 + (lane >> 5) * 8 + j;
    int n = slab * 32 + (lane & 31);
    W1F[idx] = f2b(We1[k * 128 + n]);
  } else if (idx < 65536) {                // W2F: 4 slabs x 8 ksteps
    int o = idx - 49152;
    int j = o & 7, lane = (o >> 3) & 63;
    int ks = (o >> 9) & 7, slab = o >> 12;
    int k = ks * 16 + (lane >> 5) * 8 + j;
    int n = slab * 32 + (lane & 31);
    W2F[o] = f2b(We2[k * 128 + n]);
  } else if (idx < 69632) {                // WgT [n][k], n padded 8->32
    int o = idx - 65536;
    int n = o >> 7, k = o & 127;
    WgT[o] = (n < 8) ? f2b(Wg[k * 8 + n]) : (unsigned short)0;
  } else if (idx < 118784) {               // WqkvF: 12 slabs x 8 ksteps
    int o = idx - 69632;
    int j = o & 7, lane = (o >> 3) & 63;
    int ks = (o >> 9) & 7, s = o >> 12;    // s in 0..11
    int k = ks * 16 + (lane >> 5) * 8 + j;
    int n = (s & 3) * 32 + (lane & 31);
    const float* W = (s < 4) ? Wq : (s < 8) ? Wk : Wv;
    WqkvF[o] = f2b(W[k * 128 + n]);
  } else if (idx < 119168) {               // bqkv concat
    int i = idx - 118784;
    bqkv[i] = (i < 128) ? bq[i] : (i < 256) ? bk[i - 128] : bv[i - 256];
  } else if (idx < 119168 + 20008) {
    zr[idx - 119168] = 0;                  // deg + cursor + gsum
  }
}

// ---- node QKV projection via MFMA (swapped operands: lane = node, regs = cols) ----
__global__ __launch_bounds__(256) void node_proj_k(
    const float* h, const unsigned short* WqkvF, const float* bqkv,
    unsigned short* Qb, unsigned short* Kb, unsigned short* Vb)
{
  __shared__ unsigned short hb[32][136];
  int tid = threadIdx.x;
  int n0 = blockIdx.x * 32;
#pragma unroll
  for (int i = 0; i < 4; ++i) {            // 1024 float4 = 32 rows x 32
    int gi = tid + i * 256;
    int row = gi >> 5, c4 = gi & 31;
    ushort4 u{0, 0, 0, 0};
    if (n0 + row < NN) {
      float4 v = *(const float4*)(h + (size_t)(n0 + row) * DD + c4 * 4);
      u.x = f2b(v.x); u.y = f2b(v.y); u.z = f2b(v.z); u.w = f2b(v.w);
    }
    *(ushort4*)&hb[row][c4 * 4] = u;
  }
  __syncthreads();
  int wave = tid >> 6, lane = tid & 63;
  int la = lane & 31, hi = lane >> 5;
  f32x16 aq{}, ak{}, av{};
  const unsigned short* wq = WqkvF + (((size_t)(wave)     * 8) << 9) + lane * 8;
  const unsigned short* wk = WqkvF + (((size_t)(wave + 4) * 8) << 9) + lane * 8;
  const unsigned short* wv = WqkvF + (((size_t)(wave + 8) * 8) << 9) + lane * 8;
#pragma unroll
  for (int ks = 0; ks < 8; ++ks) {
    bf16x8 x = *(const bf16x8*)&hb[la][ks * 16 + hi * 8];
    aq = mfma32(*(const bf16x8*)(wq + (ks << 9)), x, aq);   // swapped
    ak = mfma32(*(const bf16x8*)(wk + (ks << 9)), x, ak);
    av = mfma32(*(const bf16x8*)(wv + (ks << 9)), x, av);
  }
  int node = n0 + la;
  if (node < NN) {
#pragma unroll
    for (int g = 0; g < 4; ++g) {
      int cq = wave * 32 + 4 * hi + 8 * g;
      float4 b4;
      ushort4 u;
      b4 = *(const float4*)(bqkv + cq);
      u.x = f2b(aq[4*g+0] + b4.x); u.y = f2b(aq[4*g+1] + b4.y);
      u.z = f2b(aq[4*g+2] + b4.z); u.w = f2b(aq[4*g+3] + b4.w);
      *(ushort4*)(Qb + (size_t)node * DD + cq) = u;
      b4 = *(const float4*)(bqkv + 128 + cq);
      u.x = f2b(ak[4*g+0] + b4.x); u.y = f2b(ak[4*g+1] + b4.y);
      u.z = f2b(ak[4*g+2] + b4.z); u.w = f2b(ak[4*g+3] + b4.w);
      *(ushort4*)(Kb + (size_t)node * DD + cq) = u;
      b4 = *(const float4*)(bqkv + 256 + cq);
      u.x = f2b(av[4*g+0] + b4.x); u.y = f2b(av[4*g+1] + b4.y);
      u.z = f2b(av[4*g+2] + b4.z); u.w = f2b(av[4*g+3] + b4.w);
      *(ushort4*)(Vb + (size_t)node * DD + cq) = u;
    }
  }
}

// ---- logitsT[h][e] = qk/4 + bg; also builds dst-degree histogram ----
__global__ __launch_bounds__(256) void qk_k(const int* ei, const unsigned short* Qb,
                                            const unsigned short* Kb,
                                            const float* bg, float* logitsT, int* deg)
{
  int e  = blockIdx.x * 32 + (threadIdx.x & 31);
  int h8 = threadIdx.x >> 5;
  int s  = ei[e];
  int d2 = ei[NE + e];
  if (h8 == 0) atomicAdd(&deg[d2], 1);
  const ushort8v* qr = (const ushort8v*)(Qb + (size_t)d2 * DD + h8 * 16);
  const ushort8v* kr = (const ushort8v*)(Kb + (size_t)s  * DD + h8 * 16);
  ushort8v q0 = qr[0], q1 = qr[1], k0 = kr[0], k1 = kr[1];
  float acc = 0.f;
#pragma unroll
  for (int j = 0; j < 8; ++j) {
    acc += b2f(q0[j]) * b2f(k0[j]) + b2f(q1[j]) * b2f(k1[j]);
  }
  logitsT[(size_t)h8 * NE + e] = acc * 0.25f + bg[h8];
}

// ---- t gate MFMA + exp -> edge-major expE; 512 thr, (512,4) ----
__global__ __launch_bounds__(512, 4) void t_gate_k(const float* t_ij,
                                                   const unsigned short* WgT,
                                                   const float* logitsT,
                                                   float* expE, float* gsum)
{
  __shared__ unsigned short T[128][136];
  __shared__ float Gs[8][132];             // [head][edge-row in block]
  __shared__ float hpart[8];
  int tid = threadIdx.x;
  int e0 = blockIdx.x * 128;
  if (tid < 8) hpart[tid] = 0.f;
  const float4* tp = (const float4*)(t_ij + (size_t)e0 * DD);
#pragma unroll
  for (int i = 0; i < 8; ++i) {            // 4096 float4 = 128 rows x 32
    int gi = tid + i * 512;
    float4 v = tp[gi];
    int row = gi >> 5, c4 = gi & 31;
    ushort4 u; u.x = f2b(v.x); u.y = f2b(v.y); u.z = f2b(v.z); u.w = f2b(v.w);
    *(ushort4*)&T[row][c4 * 4] = u;
  }
  __syncthreads();
  int wave = tid >> 6, lane = tid & 63;
  int la = lane & 31, hi = lane >> 5;
  if (wave < 4) {                          // gate MFMA on 4 sub-tiles
    int r0 = wave * 32;
    f32x16 acc{};
    const unsigned short* wp = WgT + (size_t)la * DD + hi * 8;
#pragma unroll
    for (int ks = 0; ks < 8; ++ks) {
      bf16x8 a = *(const bf16x8*)&T[r0 + la][ks * 16 + hi * 8];
      bf16x8 b = *(const bf16x8*)(wp + ks * 16);
      acc = mfma32(a, b, acc);
    }
    if (la < 8) {
#pragma unroll
      for (int r = 0; r < 16; ++r) {
        int row = r0 + (r & 3) + 8 * (r >> 2) + 4 * hi;
        Gs[la][row] = acc[r];
      }
    }
  }
  __syncthreads();
  // exp phase: thread = (edge el = tid>>2, head-pair part = tid&3)
  int el = tid >> 2, part = tid & 3;
  int h0 = part * 2;
  float g0 = Gs[h0][el], g1 = Gs[h0 + 1][el];
  float l0 = logitsT[(size_t)h0 * NE + e0 + el];
  float l1 = logitsT[(size_t)(h0 + 1) * NE + e0 + el];
  float ex0 = exp_fast(l0 + g0);
  float ex1 = exp_fast(l1 + g1);
  float2 st; st.x = ex0; st.y = ex1;
  *(float2*)(expE + (size_t)(e0 + el) * NH + h0) = st;
  float s0 = ex0, s1 = ex1;
#pragma unroll
  for (int off = 4; off < 64; off <<= 1) {
    s0 += __shfl_xor(s0, off, 64);
    s1 += __shfl_xor(s1, off, 64);
  }
  if (lane < 4) {
    atomicAdd(&hpart[part * 2], s0);
    atomicAdd(&hpart[part * 2 + 1], s1);
  }
  __syncthreads();
  if (tid < 8) atomicAdd(&gsum[tid], hpart[tid]);
}

// ---- single-block shuffle scan over deg -> exclusive offs; also rs = 1/gsum ----
__global__ __launch_bounds__(1024) void scan_k(const int* deg, int* offs,
                                               const float* gsum, float* rs) {
  __shared__ int ws[16];
  __shared__ int tot;
  int tid = threadIdx.x;
  if (tid < 8) rs[tid] = 1.0f / gsum[tid];
  int base = tid * 10;
  int v[10]; int s = 0;
#pragma unroll
  for (int j = 0; j < 10; ++j) {
    int i = base + j;
    int d = (i < NN) ? deg[i] : 0;
    v[j] = s; s += d;
  }
  int x = s;
#pragma unroll
  for (int off = 1; off < 64; off <<= 1) {
    int y = __shfl_up(x, off, 64);
    if ((tid & 63) >= off) x += y;        // inclusive wave scan
  }
  if ((tid & 63) == 63) ws[tid >> 6] = x;
  __syncthreads();
  if (tid == 0) {
    int c = 0;
#pragma unroll
    for (int k = 0; k < 16; ++k) { int t = ws[k]; ws[k] = c; c += t; }
    tot = c;
  }
  __syncthreads();
  int texcl = ws[tid >> 6] + (x - s);     // exclusive prefix of this thread's chunk
#pragma unroll
  for (int j = 0; j < 10; ++j) {
    int i = base + j;
    if (i < NN) offs[i] = texcl + v[j];
  }
  if (tid == 0) offs[NN] = tot;
}

__global__ __launch_bounds__(256) void bucket_k(const int* ei, const int* offs,
                                                int* cursor, int2* elist2) {
  int e = blockIdx.x * 256 + threadIdx.x;
  int s = ei[e];
  int d2 = ei[NE + e];
  int p = atomicAdd(&cursor[d2], 1);
  int2 es; es.x = e; es.y = s;
  elist2[offs[d2] + p] = es;
}

// ---- gather-sum per node: h_agg[n][d] = rs * sum_e expE[e][d/16] * V[src[e]][d] ----
__global__ __launch_bounds__(128) void aggregate_k(const int* offs, const int2* elist2,
                                                   const float* expE, const float* rs,
                                                   const unsigned short* Vb, float* h_agg)
{
  int n = blockIdx.x, d = threadIdx.x;
  float rsv = rs[d >> 4];
  int hplane = d >> 4;
  int st = offs[n], en = offs[n + 1];
  float acc = 0.f;
  for (int i = st; i < en; ++i) {
    int2 es = elist2[i];
    acc += expE[(size_t)es.x * NH + hplane] * b2f(Vb[(size_t)es.y * DD + d]);
  }
  h_agg[(size_t)n * DD + d] = acc * rsv;
}

// ---- h_new = h + h_agg @ Wo + bo  (f32 to d_out, bf16 copy for MLP) ----
__global__ __launch_bounds__(128) void hnew_k(const float* h, const float* h_agg,
                                              const float* Wo, const float* bo,
                                              float* out_h, unsigned short* hnb)
{
  __shared__ float ag[4][132];
  int g = threadIdx.x >> 5, la = threadIdx.x & 31;
  int n = blockIdx.x * 4 + g;
  float4 av = *(const float4*)(h_agg + (size_t)n * DD + la * 4);
  ag[g][la*4+0] = av.x; ag[g][la*4+1] = av.y; ag[g][la*4+2] = av.z; ag[g][la*4+3] = av.w;
  __syncthreads();
  float4 acc = *(const float4*)(bo + la * 4);
  for (int kk = 0; kk < DD; ++kk) {
    float a = ag[g][kk];
    float4 w = *(const float4*)(Wo + (size_t)kk * DD + la * 4);
    acc.x += a * w.x; acc.y += a * w.y; acc.z += a * w.z; acc.w += a * w.w;
  }
  float4 hv = *(const float4*)(h + (size_t)n * DD + la * 4);
  acc.x += hv.x; acc.y += hv.y; acc.z += hv.z; acc.w += hv.w;
  *(float4*)(out_h + (size_t)n * DD + la * 4) = acc;
  ushort4 u; u.x = f2b(acc.x); u.y = f2b(acc.y); u.z = f2b(acc.z); u.w = f2b(acc.w);
  *(ushort4*)(hnb + (size_t)n * DD + la * 4) = u;
}

// ---- edge MLP, split-Ah two-pass GEMM1: LDS 35.3 KB -> 4 blocks/CU ----
// Pass A: stage h_src + t, MFMA K{src}+K{t} (Bs/Bt in regs).
// Pass B: restage Ah with h_dst, MFMA K{dst} (Bd preloaded during pass A).
__global__ __launch_bounds__(256, 4) void edge_mlp_k(
    const int* ei, const unsigned short* hnb, const float* t_ij,
    const unsigned short* W1F, const unsigned short* W2F,
    const float* be1, const float* be2, float* t_out)
{
  __shared__ unsigned short Ah[64][136];   // h_src -> h_dst -> Y
  __shared__ unsigned short Tl[64][136];   // t section (A-frags + residual)
  __shared__ int sd[128];
  int tid = threadIdx.x;
  int e0 = blockIdx.x * 64;
  int lane = tid & 63, wave = tid >> 6;
  int la = lane & 31, hi = lane >> 5;
  int n0 = wave * 32;

  const unsigned short* w1p = W1F + (((size_t)wave * 24) << 9) + lane * 8;
  bf16x8 Bs[8], Bt[8];
#pragma unroll
  for (int i = 0; i < 8; ++i) Bs[i] = *(const bf16x8*)(w1p + (i << 9));
#pragma unroll
  for (int i = 0; i < 8; ++i) Bt[i] = *(const bf16x8*)(w1p + ((16 + i) << 9));

  if (tid < 128) sd[tid] = (tid < 64) ? ei[e0 + tid] : ei[NE + e0 + tid - 64];
  __syncthreads();
#pragma unroll
  for (int i = 0; i < 4; ++i) {            // stage h_src: 1024 16B chunks
    int c = tid + i * 256;
    int row = c >> 4, cc = c & 15;
    int node = sd[row];
    *(ushort8v*)&Ah[row][cc * 8] =
        *(const ushort8v*)(hnb + (size_t)node * DD + cc * 8);
  }
#pragma unroll
  for (int i = 0; i < 4; ++i) {            // stage t: f32 -> bf16
    int c = tid + i * 256;
    int row = c >> 4, cc = c & 15;
    const float4* fp = (const float4*)(t_ij + (size_t)(e0 + row) * DD + cc * 8);
    float4 v0 = fp[0], v1 = fp[1];
    ushort4 u0; u0.x=f2b(v0.x); u0.y=f2b(v0.y); u0.z=f2b(v0.z); u0.w=f2b(v0.w);
    ushort4 u1; u1.x=f2b(v1.x); u1.y=f2b(v1.y); u1.z=f2b(v1.z); u1.w=f2b(v1.w);
    *(ushort4*)&Tl[row][cc * 8]     = u0;
    *(ushort4*)&Tl[row][cc * 8 + 4] = u1;
  }
  __syncthreads();
  f32x16 acc0{}, acc1{};
#pragma unroll
  for (int ks = 0; ks < 8; ++ks) {         // K 0..127: h_src
    bf16x8 x0 = *(const bf16x8*)&Ah[la][ks * 16 + hi * 8];
    bf16x8 x1 = *(const bf16x8*)&Ah[la + 32][ks * 16 + hi * 8];
    acc0 = mfma32(Bs[ks], x0, acc0);
    acc1 = mfma32(Bs[ks], x1, acc1);
  }
#pragma unroll
  for (int ks = 0; ks < 8; ++ks) {         // K 256..383: t
    bf16x8 x0 = *(const bf16x8*)&Tl[la][ks * 16 + hi * 8];
    bf16x8 x1 = *(const bf16x8*)&Tl[la + 32][ks * 16 + hi * 8];
    acc0 = mfma32(Bt[ks], x0, acc0);
    acc1 = mfma32(Bt[ks], x1, acc1);
  }
  bf16x8 Bd[8];
#pragma unroll
  for (int i = 0; i < 8; ++i) Bd[i] = *(const bf16x8*)(w1p + ((8 + i) << 9));
  __syncthreads();                         // all h_src reads done
#pragma unroll
  for (int i = 0; i < 4; ++i) {            // restage Ah with h_dst
    int c = tid + i * 256;
    int row = c >> 4, cc = c & 15;
    int node = sd[64 + row];
    *(ushort8v*)&Ah[row][cc * 8] =
        *(const ushort8v*)(hnb + (size_t)node * DD + cc * 8);
  }
  __syncthreads();
#pragma unroll
  for (int ks = 0; ks < 8; ++ks) {         // K 128..255: h_dst
    bf16x8 x0 = *(const bf16x8*)&Ah[la][ks * 16 + hi * 8];
    bf16x8 x1 = *(const bf16x8*)&Ah[la + 32][ks * 16 + hi * 8];
    acc0 = mfma32(Bd[ks], x0, acc0);
    acc1 = mfma32(Bd[ks], x1, acc1);
  }
  bf16x8 B2[8];
  const unsigned short* w2p = W2F + (((size_t)wave * 8) << 9) + lane * 8;
#pragma unroll
  for (int ks = 0; ks < 8; ++ks) B2[ks] = *(const bf16x8*)(w2p + (ks << 9));
  __syncthreads();                         // all h_dst reads done; Ah -> Y
  // silu -> Y: lane owns edge la / la+32; 4-consecutive cols per group
#pragma unroll
  for (int g = 0; g < 4; ++g) {
    int nb = n0 + 4 * hi + 8 * g;
    float4 bv = *(const float4*)(be1 + nb);
    ushort4 y0;
    y0.x = f2b(silu_fast(acc0[4*g+0] + bv.x));
    y0.y = f2b(silu_fast(acc0[4*g+1] + bv.y));
    y0.z = f2b(silu_fast(acc0[4*g+2] + bv.z));
    y0.w = f2b(silu_fast(acc0[4*g+3] + bv.w));
    *(ushort4*)&Ah[la][nb] = y0;
    ushort4 y1;
    y1.x = f2b(silu_fast(acc1[4*g+0] + bv.x));
    y1.y = f2b(silu_fast(acc1[4*g+1] + bv.y));
    y1.z = f2b(silu_fast(acc1[4*g+2] + bv.z));
    y1.w = f2b(silu_fast(acc1[4*g+3] + bv.w));
    *(ushort4*)&Ah[la + 32][nb] = y1;
  }
  __syncthreads();
  f32x16 d0{}, d1{};
#pragma unroll
  for (int ks = 0; ks < 8; ++ks) {
    bf16x8 x0 = *(const bf16x8*)&Ah[la][ks * 16 + hi * 8];
    bf16x8 x1 = *(const bf16x8*)&Ah[la + 32][ks * 16 + hi * 8];
    d0 = mfma32(B2[ks], x0, d0);
    d1 = mfma32(B2[ks], x1, d1);
  }
  // epilogue: residual (b64 LDS) + bias + float4 stores
#pragma unroll
  for (int g = 0; g < 4; ++g) {
    int nb = n0 + 4 * hi + 8 * g;
    float4 bv = *(const float4*)(be2 + nb);
    ushort4 r0 = *(const ushort4*)&Tl[la][nb];
    float4 o0;
    o0.x = b2f(r0.x) + d0[4*g+0] + bv.x;
    o0.y = b2f(r0.y) + d0[4*g+1] + bv.y;
    o0.z = b2f(r0.z) + d0[4*g+2] + bv.z;
    o0.w = b2f(r0.w) + d0[4*g+3] + bv.w;
    *(float4*)(t_out + (size_t)(e0 + la) * DD + nb) = o0;
    ushort4 r1 = *(const ushort4*)&Tl[la + 32][nb];
    float4 o1;
    o1.x = b2f(r1.x) + d1[4*g+0] + bv.x;
    o1.y = b2f(r1.y) + d1[4*g+1] + bv.y;
    o1.z = b2f(r1.z) + d1[4*g+2] + bv.z;
    o1.w = b2f(r1.w) + d1[4*g+3] + bv.w;
    *(float4*)(t_out + (size_t)(e0 + la + 32) * DD + nb) = o1;
  }
}

extern "C" void kernel_launch(void* const* d_in, const int* in_sizes, int n_in,
                              void* d_out, int out_size, void* d_ws, size_t ws_size,
                              hipStream_t stream)
{
  const int*   ei   = (const int*)d_in[0];
  const float* h    = (const float*)d_in[1];
  const float* t_ij = (const float*)d_in[2];
  const float* Wq = (const float*)d_in[3];
  const float* bq = (const float*)d_in[4];
  const float* Wk = (const float*)d_in[5];
  const float* bk = (const float*)d_in[6];
  const float* Wv = (const float*)d_in[7];
  const float* bv = (const float*)d_in[8];
  const float* Wg = (const float*)d_in[9];
  const float* bg = (const float*)d_in[10];
  const float* Wo = (const float*)d_in[11];
  const float* bo = (const float*)d_in[12];
  const float* We1 = (const float*)d_in[13];
  const float* be1 = (const float*)d_in[14];
  const float* We2 = (const float*)d_in[15];
  const float* be2 = (const float*)d_in[16];

  char* base = (char*)d_ws;
  size_t o = 0;
  auto take = [&](size_t bytes) -> void* {
    void* p = base + o;
    o = (o + bytes + 255) & ~(size_t)255;
    return p;
  };
  unsigned short* Qb = (unsigned short*)take((size_t)NN * DD * 2);
  unsigned short* Kb = (unsigned short*)take((size_t)NN * DD * 2);
  unsigned short* Vb = (unsigned short*)take((size_t)NN * DD * 2);
  float* logitsT = (float*)take((size_t)NH * NE * 4);
  float* expE    = (float*)take((size_t)NE * NH * 4);   // edge-major alpha
  float* rs      = (float*)take(256);
  float* h_agg   = (float*)take((size_t)NN * DD * 4);
  // zero region: deg + cursor + gsum contiguous (zeroed by prep_weights_k)
  char* zbase = base + o;
  int*   deg    = (int*)zbase;
  int*   cursor = (int*)(zbase + (size_t)NN * 4);
  float* gsum   = (float*)(zbase + (size_t)NN * 8);
  size_t zbytes = (size_t)(NN * 2 + 8) * 4;     // 20008 ints
  o = (o + zbytes + 255) & ~(size_t)255;
  int* offs    = (int*)take((size_t)(NN + 1) * 4);
  int2* elist2 = (int2*)take((size_t)NE * 8);
  unsigned short* hnb   = (unsigned short*)take((size_t)NN * DD * 2);
  unsigned short* W1F   = (unsigned short*)take(49152 * 2);
  unsigned short* W2F   = (unsigned short*)take(16384 * 2);
  unsigned short* WgT   = (unsigned short*)take(4096 * 2);
  unsigned short* WqkvF = (unsigned short*)take(49152 * 2);
  float*          bqkv  = (float*)take(384 * 4);

  float* out_h = (float*)d_out;
  float* t_out = out_h + (size_t)NN * DD;

  prep_weights_k<<<544, 256, 0, stream>>>(We1, We2, Wg, Wq, Wk, Wv, bq, bk, bv,
                                          W1F, W2F, WgT, WqkvF, bqkv, (int*)zbase);
  node_proj_k<<<(NN + 31) / 32, 256, 0, stream>>>(h, WqkvF, bqkv, Qb, Kb, Vb);
  qk_k<<<NE / 32, 256, 0, stream>>>(ei, Qb, Kb, bg, logitsT, deg);
  t_gate_k<<<NE / 128, 512, 0, stream>>>(t_ij, WgT, logitsT, expE, gsum);
  scan_k<<<1, 1024, 0, stream>>>(deg, offs, gsum, rs);
  bucket_k<<<NE / 256, 256, 0, stream>>>(ei, offs, cursor, elist2);
  aggregate_k<<<NN, 128, 0, stream>>>(offs, elist2, expE, rs, Vb, h_agg);
  hnew_k<<<NN / 4, 128, 0, stream>>>(h, h_agg, Wo, bo, out_h, hnb);
  edge_mlp_k<<<NE / 64, 256, 0, stream>>>(ei, hnb, t_ij, W1F, W2F, be1, be2, t_out);
}

// Round 16
// 273.437 us; speedup vs baseline: 1.9077x; 1.0240x over previous
//
#include <hip/hip_runtime.h>

#define NN 10000      // nodes
#define NE 320000     // edges
#define DD 128        // feature dim
#define NH 8          // heads

typedef __attribute__((ext_vector_type(8)))  __bf16        bf16x8;
typedef __attribute__((ext_vector_type(8)))  unsigned short ushort8v;
typedef __attribute__((ext_vector_type(16))) float         f32x16;

__device__ __forceinline__ unsigned short f2b(float f) {
  unsigned int b = __builtin_bit_cast(unsigned int, f);
  b += 0x7FFFu + ((b >> 16) & 1u);          // RNE to bf16
  return (unsigned short)(b >> 16);
}
__device__ __forceinline__ float b2f(unsigned short u) {
  return __builtin_bit_cast(float, (unsigned int)u << 16);
}
__device__ __forceinline__ f32x16 mfma32(bf16x8 a, bf16x8 b, f32x16 c) {
  return __builtin_amdgcn_mfma_f32_32x32x16_bf16(a, b, c, 0, 0, 0);
}
__device__ __forceinline__ float exp_fast(float x) {
  return __builtin_amdgcn_exp2f(x * 1.44269504f);
}
__device__ __forceinline__ float silu_fast(float x) {
  float e = __builtin_amdgcn_exp2f(x * -1.44269504f);
  return x * __builtin_amdgcn_rcpf(1.0f + e);
}

// ---- weights -> bf16 fragment-major + zero scratch counters ----
// Fragment-major: F[((slab*KS+ks)*64+lane)*8+j] = W[k][n],
//   k = ks*16 + (lane>>5)*8 + j, n = slab*32 + (lane&31)
__global__ __launch_bounds__(256) void prep_weights_k(
    const float* We1, const float* We2, const float* Wg,
    const float* Wq, const float* Wk, const float* Wv,
    const float* bq, const float* bk, const float* bv,
    unsigned short* W1F, unsigned short* W2F, unsigned short* WgT,
    unsigned short* WqkvF, float* bqkv, int* zr)
{
  int idx = blockIdx.x * 256 + threadIdx.x;
  if (idx < 49152) {                       // W1F: 4 slabs x 24 ksteps
    int j = idx & 7, lane = (idx >> 3) & 63;
    int ks = (idx >> 9) % 24, slab = idx / 12288;
    int k = ks * 16 + (lane >> 5) * 8 + j;
    int n = slab * 32 + (lane & 31);
    W1F[idx] = f2b(We1[k * 128 + n]);
  } else if (idx < 65536) {                // W2F: 4 slabs x 8 ksteps
    int o = idx - 49152;
    int j = o & 7, lane = (o >> 3) & 63;
    int ks = (o >> 9) & 7, slab = o >> 12;
    int k = ks * 16 + (lane >> 5) * 8 + j;
    int n = slab * 32 + (lane & 31);
    W2F[o] = f2b(We2[k * 128 + n]);
  } else if (idx < 69632) {                // WgT [n][k], n padded 8->32
    int o = idx - 65536;
    int n = o >> 7, k = o & 127;
    WgT[o] = (n < 8) ? f2b(Wg[k * 8 + n]) : (unsigned short)0;
  } else if (idx < 118784) {               // WqkvF: 12 slabs x 8 ksteps
    int o = idx - 69632;
    int j = o & 7, lane = (o >> 3) & 63;
    int ks = (o >> 9) & 7, s = o >> 12;    // s in 0..11
    int k = ks * 16 + (lane >> 5) * 8 + j;
    int n = (s & 3) * 32 + (lane & 31);
    const float* W = (s < 4) ? Wq : (s < 8) ? Wk : Wv;
    WqkvF[o] = f2b(W[k * 128 + n]);
  } else if (idx < 119168) {               // bqkv concat
    int i = idx - 118784;
    bqkv[i] = (i < 128) ? bq[i] : (i < 256) ? bk[i - 128] : bv[i - 256];
  } else if (idx < 119168 + 20008) {
    zr[idx - 119168] = 0;                  // deg + cursor + gsum
  }
}

// ---- node QKV projection via MFMA (swapped operands: lane = node, regs = cols) ----
__global__ __launch_bounds__(256) void node_proj_k(
    const float* h, const unsigned short* WqkvF, const float* bqkv,
    unsigned short* Qb, unsigned short* Kb, unsigned short* Vb)
{
  __shared__ unsigned short hb[32][136];
  int tid = threadIdx.x;
  int n0 = blockIdx.x * 32;
#pragma unroll
  for (int i = 0; i < 4; ++i) {            // 1024 float4 = 32 rows x 32
    int gi = tid + i * 256;
    int row = gi >> 5, c4 = gi & 31;
    ushort4 u{0, 0, 0, 0};
    if (n0 + row < NN) {
      float4 v = *(const float4*)(h + (size_t)(n0 + row) * DD + c4 * 4);
      u.x = f2b(v.x); u.y = f2b(v.y); u.z = f2b(v.z); u.w = f2b(v.w);
    }
    *(ushort4*)&hb[row][c4 * 4] = u;
  }
  __syncthreads();
  int wave = tid >> 6, lane = tid & 63;
  int la = lane & 31, hi = lane >> 5;
  f32x16 aq{}, ak{}, av{};
  const unsigned short* wq = WqkvF + (((size_t)(wave)     * 8) << 9) + lane * 8;
  const unsigned short* wk = WqkvF + (((size_t)(wave + 4) * 8) << 9) + lane * 8;
  const unsigned short* wv = WqkvF + (((size_t)(wave + 8) * 8) << 9) + lane * 8;
#pragma unroll
  for (int ks = 0; ks < 8; ++ks) {
    bf16x8 x = *(const bf16x8*)&hb[la][ks * 16 + hi * 8];
    aq = mfma32(*(const bf16x8*)(wq + (ks << 9)), x, aq);   // swapped
    ak = mfma32(*(const bf16x8*)(wk + (ks << 9)), x, ak);
    av = mfma32(*(const bf16x8*)(wv + (ks << 9)), x, av);
  }
  int node = n0 + la;
  if (node < NN) {
#pragma unroll
    for (int g = 0; g < 4; ++g) {
      int cq = wave * 32 + 4 * hi + 8 * g;
      float4 b4;
      ushort4 u;
      b4 = *(const float4*)(bqkv + cq);
      u.x = f2b(aq[4*g+0] + b4.x); u.y = f2b(aq[4*g+1] + b4.y);
      u.z = f2b(aq[4*g+2] + b4.z); u.w = f2b(aq[4*g+3] + b4.w);
      *(ushort4*)(Qb + (size_t)node * DD + cq) = u;
      b4 = *(const float4*)(bqkv + 128 + cq);
      u.x = f2b(ak[4*g+0] + b4.x); u.y = f2b(ak[4*g+1] + b4.y);
      u.z = f2b(ak[4*g+2] + b4.z); u.w = f2b(ak[4*g+3] + b4.w);
      *(ushort4*)(Kb + (size_t)node * DD + cq) = u;
      b4 = *(const float4*)(bqkv + 256 + cq);
      u.x = f2b(av[4*g+0] + b4.x); u.y = f2b(av[4*g+1] + b4.y);
      u.z = f2b(av[4*g+2] + b4.z); u.w = f2b(av[4*g+3] + b4.w);
      *(ushort4*)(Vb + (size_t)node * DD + cq) = u;
    }
  }
}

// ---- logitsT[h][e] = qk/4 + bg; also builds dst-degree histogram ----
__global__ __launch_bounds__(256) void qk_k(const int* ei, const unsigned short* Qb,
                                            const unsigned short* Kb,
                                            const float* bg, float* logitsT, int* deg)
{
  int e  = blockIdx.x * 32 + (threadIdx.x & 31);
  int h8 = threadIdx.x >> 5;
  int s  = ei[e];
  int d2 = ei[NE + e];
  if (h8 == 0) atomicAdd(&deg[d2], 1);
  const ushort8v* qr = (const ushort8v*)(Qb + (size_t)d2 * DD + h8 * 16);
  const ushort8v* kr = (const ushort8v*)(Kb + (size_t)s  * DD + h8 * 16);
  ushort8v q0 = qr[0], q1 = qr[1], k0 = kr[0], k1 = kr[1];
  float acc = 0.f;
#pragma unroll
  for (int j = 0; j < 8; ++j) {
    acc += b2f(q0[j]) * b2f(k0[j]) + b2f(q1[j]) * b2f(k1[j]);
  }
  logitsT[(size_t)h8 * NE + e] = acc * 0.25f + bg[h8];
}

// ---- t gate MFMA + exp -> edge-major expE; 512 thr, (512,4).
// logitsT reads PREFETCHED at kernel entry (independent of staging/MFMA). ----
__global__ __launch_bounds__(512, 4) void t_gate_k(const float* t_ij,
                                                   const unsigned short* WgT,
                                                   const float* logitsT,
                                                   float* expE, float* gsum)
{
  __shared__ unsigned short T[128][136];
  __shared__ float Gs[8][132];             // [head][edge-row in block]
  __shared__ float hpart[8];
  int tid = threadIdx.x;
  int e0 = blockIdx.x * 128;
  if (tid < 8) hpart[tid] = 0.f;
  // prefetch exp-phase logits (consumed after 2nd barrier)
  int el = tid >> 2, part = tid & 3;
  int h0 = part * 2;
  float l0 = logitsT[(size_t)h0 * NE + e0 + el];
  float l1 = logitsT[(size_t)(h0 + 1) * NE + e0 + el];
  const float4* tp = (const float4*)(t_ij + (size_t)e0 * DD);
#pragma unroll
  for (int i = 0; i < 8; ++i) {            // 4096 float4 = 128 rows x 32
    int gi = tid + i * 512;
    float4 v = tp[gi];
    int row = gi >> 5, c4 = gi & 31;
    ushort4 u; u.x = f2b(v.x); u.y = f2b(v.y); u.z = f2b(v.z); u.w = f2b(v.w);
    *(ushort4*)&T[row][c4 * 4] = u;
  }
  __syncthreads();
  int wave = tid >> 6, lane = tid & 63;
  int la = lane & 31, hi = lane >> 5;
  if (wave < 4) {                          // gate MFMA on 4 sub-tiles
    int r0 = wave * 32;
    f32x16 acc{};
    const unsigned short* wp = WgT + (size_t)la * DD + hi * 8;
#pragma unroll
    for (int ks = 0; ks < 8; ++ks) {
      bf16x8 a = *(const bf16x8*)&T[r0 + la][ks * 16 + hi * 8];
      bf16x8 b = *(const bf16x8*)(wp + ks * 16);
      acc = mfma32(a, b, acc);
    }
    if (la < 8) {
#pragma unroll
      for (int r = 0; r < 16; ++r) {
        int row = r0 + (r & 3) + 8 * (r >> 2) + 4 * hi;
        Gs[la][row] = acc[r];
      }
    }
  }
  __syncthreads();
  // exp phase: thread = (edge el, head-pair part); contiguous float2 stores.
  float g0 = Gs[h0][el], g1 = Gs[h0 + 1][el];
  float ex0 = exp_fast(l0 + g0);
  float ex1 = exp_fast(l1 + g1);
  float2 st; st.x = ex0; st.y = ex1;
  *(float2*)(expE + (size_t)(e0 + el) * NH + h0) = st;
  float s0 = ex0, s1 = ex1;
#pragma unroll
  for (int off = 4; off < 64; off <<= 1) {
    s0 += __shfl_xor(s0, off, 64);
    s1 += __shfl_xor(s1, off, 64);
  }
  if (lane < 4) {
    atomicAdd(&hpart[part * 2], s0);
    atomicAdd(&hpart[part * 2 + 1], s1);
  }
  __syncthreads();
  if (tid < 8) atomicAdd(&gsum[tid], hpart[tid]);
}

// ---- single-block shuffle scan over deg -> exclusive offs; also rs = 1/gsum ----
__global__ __launch_bounds__(1024) void scan_k(const int* deg, int* offs,
                                               const float* gsum, float* rs) {
  __shared__ int ws[16];
  __shared__ int tot;
  int tid = threadIdx.x;
  if (tid < 8) rs[tid] = 1.0f / gsum[tid];
  int base = tid * 10;
  int v[10]; int s = 0;
#pragma unroll
  for (int j = 0; j < 10; ++j) {
    int i = base + j;
    int d = (i < NN) ? deg[i] : 0;
    v[j] = s; s += d;
  }
  int x = s;
#pragma unroll
  for (int off = 1; off < 64; off <<= 1) {
    int y = __shfl_up(x, off, 64);
    if ((tid & 63) >= off) x += y;        // inclusive wave scan
  }
  if ((tid & 63) == 63) ws[tid >> 6] = x;
  __syncthreads();
  if (tid == 0) {
    int c = 0;
#pragma unroll
    for (int k = 0; k < 16; ++k) { int t = ws[k]; ws[k] = c; c += t; }
    tot = c;
  }
  __syncthreads();
  int texcl = ws[tid >> 6] + (x - s);     // exclusive prefix of this thread's chunk
#pragma unroll
  for (int j = 0; j < 10; ++j) {
    int i = base + j;
    if (i < NN) offs[i] = texcl + v[j];
  }
  if (tid == 0) offs[NN] = tot;
}

__global__ __launch_bounds__(256) void bucket_k(const int* ei, const int* offs,
                                                int* cursor, int2* elist2) {
  int e = blockIdx.x * 256 + threadIdx.x;
  int s = ei[e];
  int d2 = ei[NE + e];
  int p = atomicAdd(&cursor[d2], 1);
  int2 es; es.x = e; es.y = s;
  elist2[offs[d2] + p] = es;
}

// ---- gather-sum per node: h_agg[n][d] = rs * sum_e expE[e][d/16] * V[src[e]][d] ----
__global__ __launch_bounds__(128) void aggregate_k(const int* offs, const int2* elist2,
                                                   const float* expE, const float* rs,
                                                   const unsigned short* Vb, float* h_agg)
{
  int n = blockIdx.x, d = threadIdx.x;
  float rsv = rs[d >> 4];
  int hplane = d >> 4;
  int st = offs[n], en = offs[n + 1];
  float acc = 0.f;
  for (int i = st; i < en; ++i) {
    int2 es = elist2[i];
    acc += expE[(size_t)es.x * NH + hplane] * b2f(Vb[(size_t)es.y * DD + d]);
  }
  h_agg[(size_t)n * DD + d] = acc * rsv;
}

// ---- h_new = h + h_agg @ Wo + bo  (f32 to d_out, bf16 copy for MLP) ----
__global__ __launch_bounds__(128) void hnew_k(const float* h, const float* h_agg,
                                              const float* Wo, const float* bo,
                                              float* out_h, unsigned short* hnb)
{
  __shared__ float ag[4][132];
  int g = threadIdx.x >> 5, la = threadIdx.x & 31;
  int n = blockIdx.x * 4 + g;
  float4 av = *(const float4*)(h_agg + (size_t)n * DD + la * 4);
  ag[g][la*4+0] = av.x; ag[g][la*4+1] = av.y; ag[g][la*4+2] = av.z; ag[g][la*4+3] = av.w;
  __syncthreads();
  float4 acc = *(const float4*)(bo + la * 4);
  for (int kk = 0; kk < DD; ++kk) {
    float a = ag[g][kk];
    float4 w = *(const float4*)(Wo + (size_t)kk * DD + la * 4);
    acc.x += a * w.x; acc.y += a * w.y; acc.z += a * w.z; acc.w += a * w.w;
  }
  float4 hv = *(const float4*)(h + (size_t)n * DD + la * 4);
  acc.x += hv.x; acc.y += hv.y; acc.z += hv.z; acc.w += hv.w;
  *(float4*)(out_h + (size_t)n * DD + la * 4) = acc;
  ushort4 u; u.x = f2b(acc.x); u.y = f2b(acc.y); u.z = f2b(acc.z); u.w = f2b(acc.w);
  *(ushort4*)(hnb + (size_t)n * DD + la * 4) = u;
}

// ---- edge MLP, split-Ah two-pass GEMM1 + T14 issue-early t prefetch ----
// t_ij loads (pure HBM stream) issue FIRST; h gathers (L2) overlap their
// latency; convert/write to Tl happens last before the MFMA barrier.
__global__ __launch_bounds__(256, 4) void edge_mlp_k(
    const int* ei, const unsigned short* hnb, const float* t_ij,
    const unsigned short* W1F, const unsigned short* W2F,
    const float* be1, const float* be2, float* t_out)
{
  __shared__ unsigned short Ah[64][136];   // h_src -> h_dst -> Y
  __shared__ unsigned short Tl[64][136];   // t section (A-frags + residual)
  __shared__ int sd[128];
  int tid = threadIdx.x;
  int e0 = blockIdx.x * 64;
  int lane = tid & 63, wave = tid >> 6;
  int la = lane & 31, hi = lane >> 5;
  int n0 = wave * 32;

  // T14: issue t loads first (independent of sd/h)
  float4 tf[8];
#pragma unroll
  for (int i = 0; i < 4; ++i) {
    int c = tid + i * 256;
    int row = c >> 4, cc = c & 15;
    const float4* fp = (const float4*)(t_ij + (size_t)(e0 + row) * DD + cc * 8);
    tf[2 * i]     = fp[0];
    tf[2 * i + 1] = fp[1];
  }

  const unsigned short* w1p = W1F + (((size_t)wave * 24) << 9) + lane * 8;
  bf16x8 Bs[8], Bt[8];
#pragma unroll
  for (int i = 0; i < 8; ++i) Bs[i] = *(const bf16x8*)(w1p + (i << 9));
#pragma unroll
  for (int i = 0; i < 8; ++i) Bt[i] = *(const bf16x8*)(w1p + ((16 + i) << 9));

  if (tid < 128) sd[tid] = (tid < 64) ? ei[e0 + tid] : ei[NE + e0 + tid - 64];
  __syncthreads();
#pragma unroll
  for (int i = 0; i < 4; ++i) {            // stage h_src: 1024 16B chunks (L2 gathers)
    int c = tid + i * 256;
    int row = c >> 4, cc = c & 15;
    int node = sd[row];
    *(ushort8v*)&Ah[row][cc * 8] =
        *(const ushort8v*)(hnb + (size_t)node * DD + cc * 8);
  }
#pragma unroll
  for (int i = 0; i < 4; ++i) {            // consume t prefetch -> Tl
    int c = tid + i * 256;
    int row = c >> 4, cc = c & 15;
    float4 v0 = tf[2 * i], v1 = tf[2 * i + 1];
    ushort4 u0; u0.x=f2b(v0.x); u0.y=f2b(v0.y); u0.z=f2b(v0.z); u0.w=f2b(v0.w);
    ushort4 u1; u1.x=f2b(v1.x); u1.y=f2b(v1.y); u1.z=f2b(v1.z); u1.w=f2b(v1.w);
    *(ushort4*)&Tl[row][cc * 8]     = u0;
    *(ushort4*)&Tl[row][cc * 8 + 4] = u1;
  }
  __syncthreads();
  f32x16 acc0{}, acc1{};
#pragma unroll
  for (int ks = 0; ks < 8; ++ks) {         // K 0..127: h_src
    bf16x8 x0 = *(const bf16x8*)&Ah[la][ks * 16 + hi * 8];
    bf16x8 x1 = *(const bf16x8*)&Ah[la + 32][ks * 16 + hi * 8];
    acc0 = mfma32(Bs[ks], x0, acc0);
    acc1 = mfma32(Bs[ks], x1, acc1);
  }
#pragma unroll
  for (int ks = 0; ks < 8; ++ks) {         // K 256..383: t
    bf16x8 x0 = *(const bf16x8*)&Tl[la][ks * 16 + hi * 8];
    bf16x8 x1 = *(const bf16x8*)&Tl[la + 32][ks * 16 + hi * 8];
    acc0 = mfma32(Bt[ks], x0, acc0);
    acc1 = mfma32(Bt[ks], x1, acc1);
  }
  bf16x8 Bd[8];
#pragma unroll
  for (int i = 0; i < 8; ++i) Bd[i] = *(const bf16x8*)(w1p + ((8 + i) << 9));
  __syncthreads();                         // all h_src reads done
#pragma unroll
  for (int i = 0; i < 4; ++i) {            // restage Ah with h_dst
    int c = tid + i * 256;
    int row = c >> 4, cc = c & 15;
    int node = sd[64 + row];
    *(ushort8v*)&Ah[row][cc * 8] =
        *(const ushort8v*)(hnb + (size_t)node * DD + cc * 8);
  }
  __syncthreads();
#pragma unroll
  for (int ks = 0; ks < 8; ++ks) {         // K 128..255: h_dst
    bf16x8 x0 = *(const bf16x8*)&Ah[la][ks * 16 + hi * 8];
    bf16x8 x1 = *(const bf16x8*)&Ah[la + 32][ks * 16 + hi * 8];
    acc0 = mfma32(Bd[ks], x0, acc0);
    acc1 = mfma32(Bd[ks], x1, acc1);
  }
  bf16x8 B2[8];
  const unsigned short* w2p = W2F + (((size_t)wave * 8) << 9) + lane * 8;
#pragma unroll
  for (int ks = 0; ks < 8; ++ks) B2[ks] = *(const bf16x8*)(w2p + (ks << 9));
  __syncthreads();                         // all h_dst reads done; Ah -> Y
  // silu -> Y: lane owns edge la / la+32; 4-consecutive cols per group
#pragma unroll
  for (int g = 0; g < 4; ++g) {
    int nb = n0 + 4 * hi + 8 * g;
    float4 bv = *(const float4*)(be1 + nb);
    ushort4 y0;
    y0.x = f2b(silu_fast(acc0[4*g+0] + bv.x));
    y0.y = f2b(silu_fast(acc0[4*g+1] + bv.y));
    y0.z = f2b(silu_fast(acc0[4*g+2] + bv.z));
    y0.w = f2b(silu_fast(acc0[4*g+3] + bv.w));
    *(ushort4*)&Ah[la][nb] = y0;
    ushort4 y1;
    y1.x = f2b(silu_fast(acc1[4*g+0] + bv.x));
    y1.y = f2b(silu_fast(acc1[4*g+1] + bv.y));
    y1.z = f2b(silu_fast(acc1[4*g+2] + bv.z));
    y1.w = f2b(silu_fast(acc1[4*g+3] + bv.w));
    *(ushort4*)&Ah[la + 32][nb] = y1;
  }
  __syncthreads();
  f32x16 d0{}, d1{};
#pragma unroll
  for (int ks = 0; ks < 8; ++ks) {
    bf16x8 x0 = *(const bf16x8*)&Ah[la][ks * 16 + hi * 8];
    bf16x8 x1 = *(const bf16x8*)&Ah[la + 32][ks * 16 + hi * 8];
    d0 = mfma32(B2[ks], x0, d0);
    d1 = mfma32(B2[ks], x1, d1);
  }
  // epilogue: residual (b64 LDS) + bias + float4 stores
#pragma unroll
  for (int g = 0; g < 4; ++g) {
    int nb = n0 + 4 * hi + 8 * g;
    float4 bv = *(const float4*)(be2 + nb);
    ushort4 r0 = *(const ushort4*)&Tl[la][nb];
    float4 o0;
    o0.x = b2f(r0.x) + d0[4*g+0] + bv.x;
    o0.y = b2f(r0.y) + d0[4*g+1] + bv.y;
    o0.z = b2f(r0.z) + d0[4*g+2] + bv.z;
    o0.w = b2f(r0.w) + d0[4*g+3] + bv.w;
    *(float4*)(t_out + (size_t)(e0 + la) * DD + nb) = o0;
    ushort4 r1 = *(const ushort4*)&Tl[la + 32][nb];
    float4 o1;
    o1.x = b2f(r1.x) + d1[4*g+0] + bv.x;
    o1.y = b2f(r1.y) + d1[4*g+1] + bv.y;
    o1.z = b2f(r1.z) + d1[4*g+2] + bv.z;
    o1.w = b2f(r1.w) + d1[4*g+3] + bv.w;
    *(float4*)(t_out + (size_t)(e0 + la + 32) * DD + nb) = o1;
  }
}

extern "C" void kernel_launch(void* const* d_in, const int* in_sizes, int n_in,
                              void* d_out, int out_size, void* d_ws, size_t ws_size,
                              hipStream_t stream)
{
  const int*   ei   = (const int*)d_in[0];
  const float* h    = (const float*)d_in[1];
  const float* t_ij = (const float*)d_in[2];
  const float* Wq = (const float*)d_in[3];
  const float* bq = (const float*)d_in[4];
  const float* Wk = (const float*)d_in[5];
  const float* bk = (const float*)d_in[6];
  const float* Wv = (const float*)d_in[7];
  const float* bv = (const float*)d_in[8];
  const float* Wg = (const float*)d_in[9];
  const float* bg = (const float*)d_in[10];
  const float* Wo = (const float*)d_in[11];
  const float* bo = (const float*)d_in[12];
  const float* We1 = (const float*)d_in[13];
  const float* be1 = (const float*)d_in[14];
  const float* We2 = (const float*)d_in[15];
  const float* be2 = (const float*)d_in[16];

  char* base = (char*)d_ws;
  size_t o = 0;
  auto take = [&](size_t bytes) -> void* {
    void* p = base + o;
    o = (o + bytes + 255) & ~(size_t)255;
    return p;
  };
  unsigned short* Qb = (unsigned short*)take((size_t)NN * DD * 2);
  unsigned short* Kb = (unsigned short*)take((size_t)NN * DD * 2);
  unsigned short* Vb = (unsigned short*)take((size_t)NN * DD * 2);
  float* logitsT = (float*)take((size_t)NH * NE * 4);
  float* expE    = (float*)take((size_t)NE * NH * 4);   // edge-major alpha
  float* rs      = (float*)take(256);
  float* h_agg   = (float*)take((size_t)NN * DD * 4);
  // zero region: deg + cursor + gsum contiguous (zeroed by prep_weights_k)
  char* zbase = base + o;
  int*   deg    = (int*)zbase;
  int*   cursor = (int*)(zbase + (size_t)NN * 4);
  float* gsum   = (float*)(zbase + (size_t)NN * 8);
  size_t zbytes = (size_t)(NN * 2 + 8) * 4;     // 20008 ints
  o = (o + zbytes + 255) & ~(size_t)255;
  int* offs    = (int*)take((size_t)(NN + 1) * 4);
  int2* elist2 = (int2*)take((size_t)NE * 8);
  unsigned short* hnb   = (unsigned short*)take((size_t)NN * DD * 2);
  unsigned short* W1F   = (unsigned short*)take(49152 * 2);
  unsigned short* W2F   = (unsigned short*)take(16384 * 2);
  unsigned short* WgT   = (unsigned short*)take(4096 * 2);
  unsigned short* WqkvF = (unsigned short*)take(49152 * 2);
  float*          bqkv  = (float*)take(384 * 4);

  float* out_h = (float*)d_out;
  float* t_out = out_h + (size_t)NN * DD;

  prep_weights_k<<<544, 256, 0, stream>>>(We1, We2, Wg, Wq, Wk, Wv, bq, bk, bv,
                                          W1F, W2F, WgT, WqkvF, bqkv, (int*)zbase);
  node_proj_k<<<(NN + 31) / 32, 256, 0, stream>>>(h, WqkvF, bqkv, Qb, Kb, Vb);
  qk_k<<<NE / 32, 256, 0, stream>>>(ei, Qb, Kb, bg, logitsT, deg);
  t_gate_k<<<NE / 128, 512, 0, stream>>>(t_ij, WgT, logitsT, expE, gsum);
  scan_k<<<1, 1024, 0, stream>>>(deg, offs, gsum, rs);
  bucket_k<<<NE / 256, 256, 0, stream>>>(ei, offs, cursor, elist2);
  aggregate_k<<<NN, 128, 0, stream>>>(offs, elist2, expE, rs, Vb, h_agg);
  hnew_k<<<NN / 4, 128, 0, stream>>>(h, h_agg, Wo, bo, out_h, hnb);
  edge_mlp_k<<<NE / 64, 256, 0, stream>>>(ei, hnb, t_ij, W1F, W2F, be1, be2, t_out);
}